// Round 3
// baseline (298.680 us; speedup 1.0000x reference)
//
#include <hip/hip_runtime.h>
#include <math.h>

namespace {

typedef unsigned short u16;
typedef unsigned int   u32;
typedef __bf16 bf16x8 __attribute__((ext_vector_type(8)));
typedef float  f32x4  __attribute__((ext_vector_type(4)));

// ---- workspace layout (u16 element offsets) --------------------------------
// Sequenced so total stays at 65.3 MB (< 67.6 MB proven safe in R1):
//   prep_x writes XH/XL; per qkv: prep_w fills the single WTS slot, projg
//   consumes it; after proj, X planes are dead and AV aliases them.
constexpr size_t OFF_XH     = 0;          // [4096][1024] bf16 hi of X
constexpr size_t OFF_XL     = 4194304;
constexpr size_t OFF_WTS_HI = 8388608;    // [1024 j=h*64+k'][1024 d] (per-qkv slot)
constexpr size_t OFF_WTS_LO = 9437184;
constexpr size_t OFF_Q_HI   = 10485760;   // [32 bh][2048][64]
constexpr size_t OFF_Q_LO   = 14680064;
constexpr size_t OFF_K_HI   = 18874368;
constexpr size_t OFF_K_LO   = 23068672;
constexpr size_t OFF_VT     = 27262976;   // [32 bh][64][2048]
constexpr size_t OFF_WOT    = 31457280;   // [1024 d'][1024 c]
constexpr size_t OFF_LINV   = 32505856;   // f32[65536] viewed as 131072 u16
constexpr size_t OFF_AV_HI  = 0;          // aliases XH (dead after proj)
constexpr size_t OFF_AV_LO  = 4194304;    // aliases XL
// end = 32,636,928 u16 = 65,273,856 B

__device__ __forceinline__ u16 f2bf(float x) {            // RNE fp32 -> bf16
  union { float f; unsigned u; } v; v.f = x;
  unsigned r = v.u + 0x7FFFu + ((v.u >> 16) & 1u);
  return (u16)(r >> 16);
}
__device__ __forceinline__ float bf2f(u16 b) {
  union { unsigned u; float f; } v; v.u = (unsigned)b << 16; return v.f;
}
__device__ __forceinline__ bf16x8 frag(const u16* p) {
  return *reinterpret_cast<const bf16x8*>(p);
}
__device__ __forceinline__ f32x4 mfma16(bf16x8 a, bf16x8 b, f32x4 c) {
  return __builtin_amdgcn_mfma_f32_16x16x32_bf16(a, b, c, 0, 0, 0);
}
__device__ __forceinline__ void gload16(const void* g, void* l) {
  __builtin_amdgcn_global_load_lds(
      (const __attribute__((address_space(1))) u32*)g,
      (__attribute__((address_space(3))) u32*)l, 16, 0, 0);
}

// ---------------------------------------------------------------------------
// Prep X: split X f32 -> Xh/Xl bf16 planes (once; removes 48x reconversion).
// ---------------------------------------------------------------------------
__global__ __launch_bounds__(256) void k_prep_x(
    const float* __restrict__ X, u16* __restrict__ wsu)
{
  u16* Xh = wsu + OFF_XH;
  u16* Xl = wsu + OFF_XL;
  const size_t total = (size_t)4096 * 1024;               // 4,194,304
  size_t i = ((size_t)blockIdx.x * 256 + threadIdx.x) * 4;
  const size_t stride = (size_t)2048 * 256 * 4;
  for (; i < total; i += stride) {
    const float4 v = *(const float4*)&X[i];
    const float vv[4] = {v.x, v.y, v.z, v.w};
    ushort4 hh, ll;
    u16 h;
    h = f2bf(vv[0]); hh.x = h; ll.x = f2bf(vv[0] - bf2f(h));
    h = f2bf(vv[1]); hh.y = h; ll.y = f2bf(vv[1] - bf2f(h));
    h = f2bf(vv[2]); hh.z = h; ll.z = f2bf(vv[2] - bf2f(h));
    h = f2bf(vv[3]); hh.w = h; ll.w = f2bf(vv[3] - bf2f(h));
    *(ushort4*)&Xh[i] = hh;
    *(ushort4*)&Xl[i] = ll;
  }
}

// ---------------------------------------------------------------------------
// Prep one W: transpose + hi/lo split W[h][d][k'] -> WTS[j=h*64+k'][d]
// ---------------------------------------------------------------------------
__global__ __launch_bounds__(256) void k_prep_w(
    const float* __restrict__ W, u16* __restrict__ wsu)
{
  const int bx = blockIdx.x;                 // 256 = h(16) * dchunk(16)
  const int h = bx >> 4, dc = bx & 15;
  const int d0 = dc * 64;
  __shared__ float T[64][65];
  const int tid = threadIdx.x;
  for (int l = 0; l < 16; ++l) {
    int idx = tid + l * 256; int r = idx >> 6, c = idx & 63;  // r=d, c=k'
    T[r][c] = W[((size_t)h * 1024 + d0 + r) * 64 + c];
  }
  __syncthreads();
  u16* Wh = wsu + OFF_WTS_HI;
  u16* Wl = wsu + OFF_WTS_LO;
  for (int l = 0; l < 16; ++l) {
    int idx = tid + l * 256; int r = idx >> 6, c = idx & 63;  // r=k', c=d
    float v = T[c][r];
    u16 hi = f2bf(v);
    size_t o = (size_t)(h * 64 + r) * 1024 + d0 + c;
    Wh[o] = hi;
    Wl[o] = f2bf(v - bf2f(hi));
  }
}

// Prep: transpose W_O[c][d'] -> WOT[d'][c] (hi only; AV carries the lo term)
__global__ __launch_bounds__(256) void k_prep_wo(
    const float* __restrict__ Wo, u16* __restrict__ wsu)
{
  const int bx = blockIdx.x;                 // 256 = cchunk(16) * dchunk(16)
  const int c0 = (bx >> 4) * 64, dd0 = (bx & 15) * 64;
  __shared__ float T[64][65];
  const int tid = threadIdx.x;
  for (int l = 0; l < 16; ++l) {
    int idx = tid + l * 256; int r = idx >> 6, c = idx & 63;
    T[r][c] = Wo[(size_t)(c0 + r) * 1024 + dd0 + c];
  }
  __syncthreads();
  u16* WOT = wsu + OFF_WOT;
  for (int l = 0; l < 16; ++l) {
    int idx = tid + l * 256; int r = idx >> 6, c = idx & 63;   // r=d', c=c
    WOT[(size_t)(dd0 + r) * 1024 + c0 + c] = f2bf(T[c][r]);
  }
}

// ---------------------------------------------------------------------------
// Projection GEMM (per qkv): C[4096][1024] = X . W, 3-term split bf16.
// m97 structure: 128x64 tile, BK=64, 4 waves, global_load_lds w16, linear LDS.
// MODE 0: Q (hi/lo store)  1: K (hi/lo)  2: V (transposed single-bf16 store).
// ---------------------------------------------------------------------------
template <int MODE>
__global__ __launch_bounds__(256, 2) void k_projg(u16* __restrict__ wsu)
{
  const int bid = blockIdx.x;                // 512
  const int s  = (bid & 7) * 64 + (bid >> 3);  // XCD-chunked swizzle (512%8==0)
  const int mt = s >> 4, h = s & 15;         // mt: 32 row-tiles, h: head = col-tile
  const int gm0 = mt * 128;
  const int j0 = h * 64;

  const u16* XH = wsu + OFF_XH;
  const u16* XL = wsu + OFF_XL;
  const u16* WH = wsu + OFF_WTS_HI;
  const u16* WL = wsu + OFF_WTS_LO;

  __shared__ __align__(16) u16 lds[24576];   // Ah[128][64] Al Bh[64][64] Bl
  u16* Ah = lds;
  u16* Al = lds + 8192;
  u16* Bh = lds + 16384;
  u16* Bl = lds + 20480;

  const int tid = threadIdx.x;
  const int w = tid >> 6, l = tid & 63, lr = l & 15, lg = l >> 4;
  const int wm = w >> 1, wn = w & 1;

  const f32x4 fz = {0.f, 0.f, 0.f, 0.f};
  f32x4 acc[4][2];
  for (int i = 0; i < 4; ++i) for (int j = 0; j < 2; ++j) acc[i][j] = fz;

  for (int kt = 0; kt < 16; ++kt) {
    const int d0 = kt * 64;
    __syncthreads();                         // prev-tile readers done
    #pragma unroll
    for (int it = 0; it < 12; ++it) {
      const int c = tid + it * 256;          // 0..3071 16B-chunks
      const u16* src;
      if (c < 2048) {                        // A planes (uniform branch per it)
        const int plane = c >> 10, cc = c & 1023;
        const int r = cc >> 3, col8 = (cc & 7) * 8;
        src = (plane ? XL : XH) + (size_t)(gm0 + r) * 1024 + d0 + col8;
      } else {                               // B planes
        const int cc = c - 2048;
        const int plane = cc >> 9, c2 = cc & 511;
        const int r = c2 >> 3, col8 = (c2 & 7) * 8;
        src = (plane ? WL : WH) + (size_t)(j0 + r) * 1024 + d0 + col8;
      }
      gload16(src, lds + (size_t)c * 8);
    }
    __syncthreads();                         // vmcnt(0) drain + barrier

    #pragma unroll
    for (int ks = 0; ks < 2; ++ks) {
      bf16x8 a_h[4], a_l[4], b_h[2], b_l[2];
      #pragma unroll
      for (int mf = 0; mf < 4; ++mf) {
        const int row = wm * 64 + mf * 16 + lr;
        a_h[mf] = frag(Ah + row * 64 + ks * 32 + lg * 8);
        a_l[mf] = frag(Al + row * 64 + ks * 32 + lg * 8);
      }
      #pragma unroll
      for (int nf = 0; nf < 2; ++nf) {
        const int row = wn * 32 + nf * 16 + lr;
        b_h[nf] = frag(Bh + row * 64 + ks * 32 + lg * 8);
        b_l[nf] = frag(Bl + row * 64 + ks * 32 + lg * 8);
      }
      #pragma unroll
      for (int nf = 0; nf < 2; ++nf)
        #pragma unroll
        for (int mf = 0; mf < 4; ++mf) {
          acc[mf][nf] = mfma16(a_h[mf], b_h[nf], acc[mf][nf]);
          acc[mf][nf] = mfma16(a_h[mf], b_l[nf], acc[mf][nf]);
          acc[mf][nf] = mfma16(a_l[mf], b_h[nf], acc[mf][nf]);
        }
    }
  }

  if (MODE < 2) {        // Q/K: hi/lo planes [bh][n][64]
    u16* Ph = wsu + (MODE == 0 ? OFF_Q_HI : OFF_K_HI);
    u16* Pl = wsu + (MODE == 0 ? OFF_Q_LO : OFF_K_LO);
    #pragma unroll
    for (int mf = 0; mf < 4; ++mf)
      #pragma unroll
      for (int nf = 0; nf < 2; ++nf)
        #pragma unroll
        for (int r = 0; r < 4; ++r) {
          const float v = acc[mf][nf][r];
          const int gn = gm0 + wm * 64 + mf * 16 + lg * 4 + r;
          const int b = gn >> 11, n = gn & 2047;
          const int kp = wn * 32 + nf * 16 + lr;
          const size_t o = ((size_t)(b * 16 + h) * 2048 + n) * 64 + kp;
          const u16 hi = f2bf(v);
          Ph[o] = hi;
          Pl[o] = f2bf(v - bf2f(hi));
        }
  } else {               // V: transposed store VT[bh][k'][n], 4n packed
    u16* VT = wsu + OFF_VT;
    #pragma unroll
    for (int mf = 0; mf < 4; ++mf)
      #pragma unroll
      for (int nf = 0; nf < 2; ++nf) {
        const int gn = gm0 + wm * 64 + mf * 16 + lg * 4;   // 4 consecutive n
        const int b = gn >> 11, n = gn & 2047;
        const int kp = wn * 32 + nf * 16 + lr;
        ushort4 p;
        p.x = f2bf(acc[mf][nf][0]); p.y = f2bf(acc[mf][nf][1]);
        p.z = f2bf(acc[mf][nf][2]); p.w = f2bf(acc[mf][nf][3]);
        *(ushort4*)&VT[((size_t)(b * 16 + h) * 64 + kp) * 2048 + n] = p;
      }
  }
}

// ---------------------------------------------------------------------------
// Pass 1: l_j = sum_i exp(S_ij)  (no max needed: |S| <~ 25, fp32-safe)
// ---------------------------------------------------------------------------
__global__ __launch_bounds__(256, 2) void k_pass1(
    u16* __restrict__ wsu, float* __restrict__ Linv)
{
  const int bx = blockIdx.x;                 // 512
  const int jt = bx & 15, bh = bx >> 4;
  const int j0 = jt * 128;
  const u16* Qh = wsu + OFF_Q_HI + (size_t)bh * 131072;
  const u16* Ql = wsu + OFF_Q_LO + (size_t)bh * 131072;
  const u16* Kh = wsu + OFF_K_HI + (size_t)bh * 131072;
  const u16* Kl = wsu + OFF_K_LO + (size_t)bh * 131072;

  __shared__ __align__(16) u16 Qsh[64][72], Qsl[64][72];

  const int tid = threadIdx.x;
  const int w = tid >> 6, l = tid & 63, lr = l & 15, lg = l >> 4;

  bf16x8 kh[2][2], kl[2][2];                 // A operand: K rows (j) in regs
  #pragma unroll
  for (int m = 0; m < 2; ++m)
    #pragma unroll
    for (int ks = 0; ks < 2; ++ks) {
      const size_t o = (size_t)(j0 + w * 32 + m * 16 + lr) * 64 + ks * 32 + lg * 8;
      kh[m][ks] = frag(&Kh[o]);
      kl[m][ks] = frag(&Kl[o]);
    }

  const f32x4 fz = {0.f, 0.f, 0.f, 0.f};
  float rsum[2][4] = {};

  for (int it = 0; it < 32; ++it) {
    const int i0 = it * 64;
    __syncthreads();
    for (int s = 0; s < 4; ++s) {
      int idx = tid + s * 256;
      int plane = idx >> 9, i2 = idx & 511;
      int r = i2 >> 3, c8 = (i2 & 7) * 8;
      const u16* src = (plane ? Ql : Qh) + (size_t)(i0 + r) * 64 + c8;
      u16* dst = plane ? &Qsl[r][c8] : &Qsh[r][c8];
      *(uint4*)dst = *(const uint4*)src;
    }
    __syncthreads();
    f32x4 s_[2][4];
    for (int m = 0; m < 2; ++m) for (int nf = 0; nf < 4; ++nf) s_[m][nf] = fz;
    #pragma unroll
    for (int nf = 0; nf < 4; ++nf)
      #pragma unroll
      for (int ks = 0; ks < 2; ++ks) {
        const int row = nf * 16 + lr, col = ks * 32 + lg * 8;
        bf16x8 qhf = frag(&Qsh[row][col]);
        bf16x8 qlf = frag(&Qsl[row][col]);
        #pragma unroll
        for (int m = 0; m < 2; ++m) {
          s_[m][nf] = mfma16(kh[m][ks], qhf, s_[m][nf]);
          s_[m][nf] = mfma16(kh[m][ks], qlf, s_[m][nf]);
          s_[m][nf] = mfma16(kl[m][ks], qhf, s_[m][nf]);
        }
      }
    #pragma unroll
    for (int m = 0; m < 2; ++m)
      #pragma unroll
      for (int r = 0; r < 4; ++r) {
        float a = 0.f;
        #pragma unroll
        for (int nf = 0; nf < 4; ++nf) a += __expf(s_[m][nf][r]);
        rsum[m][r] += a;
      }
  }
  #pragma unroll
  for (int m = 0; m < 2; ++m)
    #pragma unroll
    for (int r = 0; r < 4; ++r) {
      float v = rsum[m][r];
      v += __shfl_xor(v, 1); v += __shfl_xor(v, 2);
      v += __shfl_xor(v, 4); v += __shfl_xor(v, 8);
      if (lr == 0)
        Linv[(size_t)bh * 2048 + j0 + w * 32 + m * 16 + lg * 4 + r] = 1.0f / v;
    }
}

// ---------------------------------------------------------------------------
// Pass 2: AV[i][c] = sum_j exp(S_ij) * Linv_j * V[j][c]
// ---------------------------------------------------------------------------
__global__ __launch_bounds__(256, 2) void k_pass2(
    u16* __restrict__ wsu, const float* __restrict__ Linv)
{
  const int bx = blockIdx.x;                 // 512
  const int itile = bx & 15, bh = bx >> 4;
  const int i0 = itile * 128;
  const u16* Qh = wsu + OFF_Q_HI + (size_t)bh * 131072;
  const u16* Ql = wsu + OFF_Q_LO + (size_t)bh * 131072;
  const u16* Kh = wsu + OFF_K_HI + (size_t)bh * 131072;
  const u16* Kl = wsu + OFF_K_LO + (size_t)bh * 131072;
  const u16* VT = wsu + OFF_VT   + (size_t)bh * 131072;

  __shared__ __align__(16) u16 Ksh[64][72], Ksl[64][72];
  __shared__ __align__(16) u16 Ps[128][72];
  __shared__ __align__(16) u16 Vs[64][72];
  __shared__ float Ls[64];

  const int tid = threadIdx.x;
  const int w = tid >> 6, l = tid & 63, lr = l & 15, lg = l >> 4;

  bf16x8 qh[2][2], ql[2][2];
  #pragma unroll
  for (int m = 0; m < 2; ++m)
    #pragma unroll
    for (int ks = 0; ks < 2; ++ks) {
      const size_t o = (size_t)(i0 + w * 32 + m * 16 + lr) * 64 + ks * 32 + lg * 8;
      qh[m][ks] = frag(&Qh[o]);
      ql[m][ks] = frag(&Ql[o]);
    }

  const f32x4 fz = {0.f, 0.f, 0.f, 0.f};
  f32x4 av[2][4];
  for (int m = 0; m < 2; ++m) for (int nf = 0; nf < 4; ++nf) av[m][nf] = fz;

  for (int jt = 0; jt < 32; ++jt) {
    const int j0 = jt * 64;
    __syncthreads();
    for (int s = 0; s < 4; ++s) {            // K hi/lo: 1024 uint4
      int idx = tid + s * 256;
      int plane = idx >> 9, i2 = idx & 511;
      int r = i2 >> 3, c8 = (i2 & 7) * 8;
      const u16* src = (plane ? Kl : Kh) + (size_t)(j0 + r) * 64 + c8;
      u16* dst = plane ? &Ksl[r][c8] : &Ksh[r][c8];
      *(uint4*)dst = *(const uint4*)src;
    }
    {                                        // V^T tile: 512 uint4
      int idx = tid;
      #pragma unroll
      for (int s = 0; s < 2; ++s, idx += 256) {
        int r = idx >> 3, c8 = (idx & 7) * 8;
        *(uint4*)&Vs[r][c8] = *(const uint4*)(VT + (size_t)r * 2048 + j0 + c8);
      }
    }
    if (tid < 64) Ls[tid] = Linv[(size_t)bh * 2048 + j0 + tid];
    __syncthreads();

    f32x4 s_[2][4];
    for (int m = 0; m < 2; ++m) for (int nf = 0; nf < 4; ++nf) s_[m][nf] = fz;
    #pragma unroll
    for (int nf = 0; nf < 4; ++nf)
      #pragma unroll
      for (int ks = 0; ks < 2; ++ks) {
        const int row = nf * 16 + lr, col = ks * 32 + lg * 8;
        bf16x8 bhf = frag(&Ksh[row][col]);
        bf16x8 blf = frag(&Ksl[row][col]);
        #pragma unroll
        for (int m = 0; m < 2; ++m) {
          s_[m][nf] = mfma16(qh[m][ks], bhf, s_[m][nf]);
          s_[m][nf] = mfma16(qh[m][ks], blf, s_[m][nf]);
          s_[m][nf] = mfma16(ql[m][ks], bhf, s_[m][nf]);
        }
      }
    #pragma unroll
    for (int nf = 0; nf < 4; ++nf) {
      const float linv = Ls[nf * 16 + lr];
      #pragma unroll
      for (int m = 0; m < 2; ++m)
        #pragma unroll
        for (int r = 0; r < 4; ++r) {
          const int row = w * 32 + m * 16 + lg * 4 + r;
          Ps[row][nf * 16 + lr] = f2bf(__expf(s_[m][nf][r]) * linv);
        }
    }
    __syncthreads();
    #pragma unroll
    for (int ks = 0; ks < 2; ++ks) {
      bf16x8 pa[2];
      #pragma unroll
      for (int m = 0; m < 2; ++m)
        pa[m] = frag(&Ps[w * 32 + m * 16 + lr][ks * 32 + lg * 8]);
      #pragma unroll
      for (int nf = 0; nf < 4; ++nf) {
        bf16x8 vb = frag(&Vs[nf * 16 + lr][ks * 32 + lg * 8]);
        #pragma unroll
        for (int m = 0; m < 2; ++m) av[m][nf] = mfma16(pa[m], vb, av[m][nf]);
      }
    }
  }
  u16* AVh = wsu + OFF_AV_HI;
  u16* AVl = wsu + OFF_AV_LO;
  #pragma unroll
  for (int m = 0; m < 2; ++m)
    #pragma unroll
    for (int nf = 0; nf < 4; ++nf)
      #pragma unroll
      for (int r = 0; r < 4; ++r) {
        float v = av[m][nf][r];
        const size_t g = (size_t)bh * 2048 + i0 + w * 32 + m * 16 + lg * 4 + r;
        const int c = nf * 16 + lr;
        u16 hi = f2bf(v);
        AVh[g * 64 + c] = hi;
        AVl[g * 64 + c] = f2bf(v - bf2f(hi));
      }
}

// ---------------------------------------------------------------------------
// Output projection: Out = (AVhi+AVlo)[4096][1024] . WO  (2-term split)
// ---------------------------------------------------------------------------
__global__ __launch_bounds__(256, 2) void k_outproj(
    const u16* __restrict__ wsu, float* __restrict__ Out)
{
  const int bx = blockIdx.x;                 // 256 = gm(32) * dn(8)
  const int gm = bx >> 3, dn = bx & 7;
  const int g0 = gm * 128, d0 = dn * 128;
  const u16* AVh = wsu + OFF_AV_HI;
  const u16* AVl = wsu + OFF_AV_LO;
  const u16* WOT = wsu + OFF_WOT;

  __shared__ __align__(16) u16 Ah[128][72], Al[128][72], Bs[128][72];

  const int tid = threadIdx.x;
  const int w = tid >> 6, l = tid & 63, lr = l & 15, lg = l >> 4;
  const int wm = w >> 1, wn = w & 1;

  const f32x4 fz = {0.f, 0.f, 0.f, 0.f};
  f32x4 acc[4][4];
  for (int i = 0; i < 4; ++i) for (int j = 0; j < 4; ++j) acc[i][j] = fz;

  for (int kt = 0; kt < 16; ++kt) {
    const int c0 = kt * 64;
    __syncthreads();
    for (int s = 0; s < 12; ++s) {           // 3 planes x 1024 uint4
      int idx = tid + s * 256;
      int sel = idx >> 10, i2 = idx & 1023;
      int r = i2 >> 3, c8 = (i2 & 7) * 8;
      const u16* src = sel == 0 ? AVh + (size_t)(g0 + r) * 1024 + c0 + c8
                     : sel == 1 ? AVl + (size_t)(g0 + r) * 1024 + c0 + c8
                                : WOT + (size_t)(d0 + r) * 1024 + c0 + c8;
      u16* dst = sel == 0 ? &Ah[r][c8] : sel == 1 ? &Al[r][c8] : &Bs[r][c8];
      *(uint4*)dst = *(const uint4*)src;
    }
    __syncthreads();
    #pragma unroll
    for (int ks = 0; ks < 2; ++ks) {
      bf16x8 ah[4], al[4];
      #pragma unroll
      for (int mf = 0; mf < 4; ++mf) {
        ah[mf] = frag(&Ah[wm * 64 + mf * 16 + lr][ks * 32 + lg * 8]);
        al[mf] = frag(&Al[wm * 64 + mf * 16 + lr][ks * 32 + lg * 8]);
      }
      #pragma unroll
      for (int nf = 0; nf < 4; ++nf) {
        bf16x8 bfv = frag(&Bs[wn * 64 + nf * 16 + lr][ks * 32 + lg * 8]);
        #pragma unroll
        for (int mf = 0; mf < 4; ++mf) {
          acc[mf][nf] = mfma16(ah[mf], bfv, acc[mf][nf]);
          acc[mf][nf] = mfma16(al[mf], bfv, acc[mf][nf]);
        }
      }
    }
  }
  #pragma unroll
  for (int mf = 0; mf < 4; ++mf)
    #pragma unroll
    for (int nf = 0; nf < 4; ++nf)
      #pragma unroll
      for (int r = 0; r < 4; ++r) {
        const int g = g0 + wm * 64 + mf * 16 + lg * 4 + r;
        const int d = d0 + wn * 64 + nf * 16 + lr;
        Out[(size_t)g * 1024 + d] = acc[mf][nf][r];
      }
}

} // anonymous namespace

extern "C" void kernel_launch(void* const* d_in, const int* in_sizes, int n_in,
                              void* d_out, int out_size, void* d_ws, size_t ws_size,
                              hipStream_t stream) {
  const float* X  = (const float*)d_in[0];
  const float* Wq = (const float*)d_in[1];
  const float* Wk = (const float*)d_in[2];
  const float* Wv = (const float*)d_in[3];
  const float* Wo = (const float*)d_in[4];
  float* out = (float*)d_out;
  u16* wsu = (u16*)d_ws;
  float* Linv = (float*)(wsu + OFF_LINV);

  k_prep_x   <<<2048, 256, 0, stream>>>(X, wsu);
  k_prep_wo  <<<256,  256, 0, stream>>>(Wo, wsu);
  k_prep_w   <<<256,  256, 0, stream>>>(Wq, wsu);
  k_projg<0> <<<512,  256, 0, stream>>>(wsu);
  k_prep_w   <<<256,  256, 0, stream>>>(Wk, wsu);
  k_projg<1> <<<512,  256, 0, stream>>>(wsu);
  k_prep_w   <<<256,  256, 0, stream>>>(Wv, wsu);
  k_projg<2> <<<512,  256, 0, stream>>>(wsu);
  k_pass1    <<<512,  256, 0, stream>>>(wsu, Linv);
  k_pass2    <<<512,  256, 0, stream>>>(wsu, Linv);
  k_outproj  <<<256,  256, 0, stream>>>(wsu, out);
}

// Round 5
// 295.732 us; speedup vs baseline: 1.0100x; 1.0100x over previous
//
#include <hip/hip_runtime.h>
#include <math.h>

namespace {

typedef unsigned short u16;
typedef unsigned int   u32;
typedef __bf16 bf16x8 __attribute__((ext_vector_type(8)));
typedef float  f32x4  __attribute__((ext_vector_type(4)));
typedef float  f32x16 __attribute__((ext_vector_type(16)));
typedef u32    u32x4  __attribute__((ext_vector_type(4)));

// ---- workspace layout (u16 element offsets) --------------------------------
constexpr size_t OFF_XH     = 0;          // [4096][1024] bf16 hi of X
constexpr size_t OFF_XL     = 4194304;
constexpr size_t OFF_WTS_HI = 8388608;    // [1024 j=h*64+k'][1024 d] (per-qkv slot)
constexpr size_t OFF_WTS_LO = 9437184;
constexpr size_t OFF_Q_HI   = 10485760;   // [32 bh][2048][64]
constexpr size_t OFF_Q_LO   = 14680064;
constexpr size_t OFF_K_HI   = 18874368;
constexpr size_t OFF_K_LO   = 23068672;
constexpr size_t OFF_VT     = 27262976;   // [32 bh][64][2048]
constexpr size_t OFF_WOT    = 31457280;   // [1024 d'][1024 c]
constexpr size_t OFF_LINV   = 32505856;   // f32[65536] viewed as 131072 u16
constexpr size_t OFF_AV_HI  = 0;          // aliases XH (dead after proj)
constexpr size_t OFF_AV_LO  = 4194304;    // aliases XL
// end = 65,273,856 B (< 67.6 MB proven safe in R1)

constexpr size_t VT_ELEMS = (size_t)32 * 64 * 2048;       // 4,194,304

__device__ __forceinline__ u16 f2bf(float x) {            // RNE fp32 -> bf16
  union { float f; unsigned u; } v; v.f = x;
  unsigned r = v.u + 0x7FFFu + ((v.u >> 16) & 1u);
  return (u16)(r >> 16);
}
__device__ __forceinline__ float bf2f(u16 b) {
  union { unsigned u; float f; } v; v.u = (unsigned)b << 16; return v.f;
}
__device__ __forceinline__ bf16x8 frag(const u16* p) {
  return *reinterpret_cast<const bf16x8*>(p);
}
__device__ __forceinline__ f32x4 mfma16(bf16x8 a, bf16x8 b, f32x4 c) {
  return __builtin_amdgcn_mfma_f32_16x16x32_bf16(a, b, c, 0, 0, 0);
}
__device__ __forceinline__ f32x16 mfma32(bf16x8 a, bf16x8 b, f32x16 c) {
  return __builtin_amdgcn_mfma_f32_32x32x16_bf16(a, b, c, 0, 0, 0);
}
__device__ __forceinline__ void gload16(const void* g, void* l) {
  __builtin_amdgcn_global_load_lds(
      (const __attribute__((address_space(1))) u32*)g,
      (__attribute__((address_space(3))) u32*)l, 16, 0, 0);
}
// pack two f32 -> one u32 of 2 bf16 (lo in low half)
__device__ __forceinline__ u32 pkbf(float lo, float hi) {
  return (u32)f2bf(lo) | ((u32)f2bf(hi) << 16);
}

// ---------------------------------------------------------------------------
// Prep X: split X f32 -> Xh/Xl bf16 planes.
// ---------------------------------------------------------------------------
__global__ __launch_bounds__(256) void k_prep_x(
    const float* __restrict__ X, u16* __restrict__ wsu)
{
  u16* Xh = wsu + OFF_XH;
  u16* Xl = wsu + OFF_XL;
  const size_t total = (size_t)4096 * 1024;
  size_t i = ((size_t)blockIdx.x * 256 + threadIdx.x) * 4;
  const size_t stride = (size_t)2048 * 256 * 4;
  for (; i < total; i += stride) {
    const float4 v = *(const float4*)&X[i];
    const float vv[4] = {v.x, v.y, v.z, v.w};
    ushort4 hh, ll;
    u16 h;
    h = f2bf(vv[0]); hh.x = h; ll.x = f2bf(vv[0] - bf2f(h));
    h = f2bf(vv[1]); hh.y = h; ll.y = f2bf(vv[1] - bf2f(h));
    h = f2bf(vv[2]); hh.z = h; ll.z = f2bf(vv[2] - bf2f(h));
    h = f2bf(vv[3]); hh.w = h; ll.w = f2bf(vv[3] - bf2f(h));
    *(ushort4*)&Xh[i] = hh;
    *(ushort4*)&Xl[i] = ll;
  }
}

// ---------------------------------------------------------------------------
// Prep one W: transpose + hi/lo split W[h][d][k'] -> WTS[j=h*64+k'][d]
// ---------------------------------------------------------------------------
__global__ __launch_bounds__(256) void k_prep_w(
    const float* __restrict__ W, u16* __restrict__ wsu)
{
  const int bx = blockIdx.x;                 // 256 = h(16) * dchunk(16)
  const int h = bx >> 4, dc = bx & 15;
  const int d0 = dc * 64;
  __shared__ float T[64][65];
  const int tid = threadIdx.x;
  for (int l = 0; l < 16; ++l) {
    int idx = tid + l * 256; int r = idx >> 6, c = idx & 63;  // r=d, c=k'
    T[r][c] = W[((size_t)h * 1024 + d0 + r) * 64 + c];
  }
  __syncthreads();
  u16* Wh = wsu + OFF_WTS_HI;
  u16* Wl = wsu + OFF_WTS_LO;
  for (int l = 0; l < 16; ++l) {
    int idx = tid + l * 256; int r = idx >> 6, c = idx & 63;  // r=k', c=d
    float v = T[c][r];
    u16 hi = f2bf(v);
    size_t o = (size_t)(h * 64 + r) * 1024 + d0 + c;
    Wh[o] = hi;
    Wl[o] = f2bf(v - bf2f(hi));
  }
}

// Prep: transpose W_O[c][d'] -> WOT[d'][c]
__global__ __launch_bounds__(256) void k_prep_wo(
    const float* __restrict__ Wo, u16* __restrict__ wsu)
{
  const int bx = blockIdx.x;
  const int c0 = (bx >> 4) * 64, dd0 = (bx & 15) * 64;
  __shared__ float T[64][65];
  const int tid = threadIdx.x;
  for (int l = 0; l < 16; ++l) {
    int idx = tid + l * 256; int r = idx >> 6, c = idx & 63;
    T[r][c] = Wo[(size_t)(c0 + r) * 1024 + dd0 + c];
  }
  __syncthreads();
  u16* WOT = wsu + OFF_WOT;
  for (int l = 0; l < 16; ++l) {
    int idx = tid + l * 256; int r = idx >> 6, c = idx & 63;
    WOT[(size_t)(dd0 + r) * 1024 + c0 + c] = f2bf(T[c][r]);
  }
}

// ---------------------------------------------------------------------------
// Projection GEMM (per qkv): C[4096][1024] = X . W, 3-term split bf16.
// ---------------------------------------------------------------------------
template <int MODE>
__global__ __launch_bounds__(256, 2) void k_projg(u16* __restrict__ wsu)
{
  const int bid = blockIdx.x;                // 512
  const int s  = (bid & 7) * 64 + (bid >> 3);
  const int mt = s >> 4, h = s & 15;
  const int gm0 = mt * 128;
  const int j0 = h * 64;

  const u16* XH = wsu + OFF_XH;
  const u16* XL = wsu + OFF_XL;
  const u16* WH = wsu + OFF_WTS_HI;
  const u16* WL = wsu + OFF_WTS_LO;

  __shared__ __align__(16) u16 lds[24576];   // Ah[128][64] Al Bh[64][64] Bl
  u16* Ah = lds;
  u16* Al = lds + 8192;
  u16* Bh = lds + 16384;
  u16* Bl = lds + 20480;

  const int tid = threadIdx.x;
  const int w = tid >> 6, l = tid & 63, lr = l & 15, lg = l >> 4;
  const int wm = w >> 1, wn = w & 1;

  const f32x4 fz = {0.f, 0.f, 0.f, 0.f};
  f32x4 acc[4][2];
  for (int i = 0; i < 4; ++i) for (int j = 0; j < 2; ++j) acc[i][j] = fz;

  for (int kt = 0; kt < 16; ++kt) {
    const int d0 = kt * 64;
    __syncthreads();
    #pragma unroll
    for (int it = 0; it < 12; ++it) {
      const int c = tid + it * 256;
      const u16* src;
      if (c < 2048) {
        const int plane = c >> 10, cc = c & 1023;
        const int r = cc >> 3, col8 = (cc & 7) * 8;
        src = (plane ? XL : XH) + (size_t)(gm0 + r) * 1024 + d0 + col8;
      } else {
        const int cc = c - 2048;
        const int plane = cc >> 9, c2 = cc & 511;
        const int r = c2 >> 3, col8 = (c2 & 7) * 8;
        src = (plane ? WL : WH) + (size_t)(j0 + r) * 1024 + d0 + col8;
      }
      gload16(src, lds + (size_t)c * 8);
    }
    __syncthreads();

    #pragma unroll
    for (int ks = 0; ks < 2; ++ks) {
      bf16x8 a_h[4], a_l[4], b_h[2], b_l[2];
      #pragma unroll
      for (int mf = 0; mf < 4; ++mf) {
        const int row = wm * 64 + mf * 16 + lr;
        a_h[mf] = frag(Ah + row * 64 + ks * 32 + lg * 8);
        a_l[mf] = frag(Al + row * 64 + ks * 32 + lg * 8);
      }
      #pragma unroll
      for (int nf = 0; nf < 2; ++nf) {
        const int row = wn * 32 + nf * 16 + lr;
        b_h[nf] = frag(Bh + row * 64 + ks * 32 + lg * 8);
        b_l[nf] = frag(Bl + row * 64 + ks * 32 + lg * 8);
      }
      #pragma unroll
      for (int nf = 0; nf < 2; ++nf)
        #pragma unroll
        for (int mf = 0; mf < 4; ++mf) {
          acc[mf][nf] = mfma16(a_h[mf], b_h[nf], acc[mf][nf]);
          acc[mf][nf] = mfma16(a_h[mf], b_l[nf], acc[mf][nf]);
          acc[mf][nf] = mfma16(a_l[mf], b_h[nf], acc[mf][nf]);
        }
    }
  }

  if (MODE < 2) {
    u16* Ph = wsu + (MODE == 0 ? OFF_Q_HI : OFF_K_HI);
    u16* Pl = wsu + (MODE == 0 ? OFF_Q_LO : OFF_K_LO);
    #pragma unroll
    for (int mf = 0; mf < 4; ++mf)
      #pragma unroll
      for (int nf = 0; nf < 2; ++nf)
        #pragma unroll
        for (int r = 0; r < 4; ++r) {
          const float v = acc[mf][nf][r];
          const int gn = gm0 + wm * 64 + mf * 16 + lg * 4 + r;
          const int b = gn >> 11, n = gn & 2047;
          const int kp = wn * 32 + nf * 16 + lr;
          const size_t o = ((size_t)(b * 16 + h) * 2048 + n) * 64 + kp;
          const u16 hi = f2bf(v);
          Ph[o] = hi;
          Pl[o] = f2bf(v - bf2f(hi));
        }
  } else {
    u16* VT = wsu + OFF_VT;
    #pragma unroll
    for (int mf = 0; mf < 4; ++mf)
      #pragma unroll
      for (int nf = 0; nf < 2; ++nf) {
        const int gn = gm0 + wm * 64 + mf * 16 + lg * 4;
        const int b = gn >> 11, n = gn & 2047;
        const int kp = wn * 32 + nf * 16 + lr;
        ushort4 p;
        p.x = f2bf(acc[mf][nf][0]); p.y = f2bf(acc[mf][nf][1]);
        p.z = f2bf(acc[mf][nf][2]); p.w = f2bf(acc[mf][nf][3]);
        *(ushort4*)&VT[((size_t)(b * 16 + h) * 64 + kp) * 2048 + n] = p;
      }
  }
}

// ---------------------------------------------------------------------------
// Pass 1 (32x32 swapped): l_j = sum_i exp(S_ij).
// ---------------------------------------------------------------------------
__global__ __launch_bounds__(256, 2) void k_pass1(
    u16* __restrict__ wsu, float* __restrict__ Linv)
{
  const int bid = blockIdx.x;                  // 512
  const int swz = (bid & 7) * 64 + (bid >> 3); // same-bh blocks share an XCD
  const int jtile = swz & 15, bh = swz >> 4;
  const int j0 = jtile * 128;
  const u16* Qh = wsu + OFF_Q_HI + (size_t)bh * 131072;
  const u16* Ql = wsu + OFF_Q_LO + (size_t)bh * 131072;
  const u16* Kh = wsu + OFF_K_HI + (size_t)bh * 131072;
  const u16* Kl = wsu + OFF_K_LO + (size_t)bh * 131072;

  __shared__ __align__(16) u16 lds[2][2][4096];   // [buf][Qhi,Qlo][64][64]

  const int tid = threadIdx.x;
  const int w = tid >> 6, l = tid & 63;
  const int il = l & 31, hi = l >> 5;

  // stationary K A-frags (row=j, k=d)
  bf16x8 kah[4], kal[4];
  {
    const int jrow = j0 + w * 32 + il;
    #pragma unroll
    for (int ks = 0; ks < 4; ++ks) {
      const size_t o = (size_t)jrow * 64 + ks * 16 + hi * 8;
      kah[ks] = frag(&Kh[o]);
      kal[ks] = frag(&Kl[o]);
    }
  }

  auto stage = [&](int buf, int ic) {
    const int i0 = ic * 64;
    #pragma unroll
    for (int it = 0; it < 4; ++it) {
      const int c = tid + it * 256;            // 0..1023
      const int plane = c >> 9, cc = c & 511;
      const int r = cc >> 3, cl = cc & 7;
      const int sw8 = (cl ^ (r & 7)) * 8;      // inverse-swizzled source
      const u16* src = (plane ? Ql : Qh) + (size_t)(i0 + r) * 64 + sw8;
      gload16(src, &lds[buf][0][0] + (size_t)c * 8);
    }
  };

  const f32x16 fz16 = {0,0,0,0,0,0,0,0,0,0,0,0,0,0,0,0};
  float lsum[16] = {};

  stage(0, 0);
  __syncthreads();
  int cur = 0;
  for (int ic = 0; ic < 32; ++ic) {
    if (ic < 31) stage(cur ^ 1, ic + 1);
    const u16* Qsh = &lds[cur][0][0];
    const u16* Qsl = &lds[cur][1][0];
    #pragma unroll
    for (int it2 = 0; it2 < 2; ++it2) {
      f32x16 s = fz16;
      #pragma unroll
      for (int ks = 0; ks < 4; ++ks) {
        const int qrow = it2 * 32 + il;
        const int ch = ((ks * 2 + hi) ^ (qrow & 7)) * 8;   // swizzled read
        bf16x8 qb  = frag(&Qsh[qrow * 64 + ch]);
        bf16x8 qbl = frag(&Qsl[qrow * 64 + ch]);
        s = mfma32(kah[ks], qb,  s);
        s = mfma32(kah[ks], qbl, s);
        s = mfma32(kal[ks], qb,  s);
      }
      #pragma unroll
      for (int r = 0; r < 16; ++r) lsum[r] += __expf(s[r]);
    }
    __syncthreads();
    cur ^= 1;
  }

  #pragma unroll
  for (int r = 0; r < 16; ++r) {
    float v = lsum[r];
    v += __shfl_xor(v, 1);  v += __shfl_xor(v, 2);
    v += __shfl_xor(v, 4);  v += __shfl_xor(v, 8);
    v += __shfl_xor(v, 16);
    if (il == 0) {
      const int j = j0 + w * 32 + (r & 3) + 8 * (r >> 2) + 4 * hi;
      Linv[(size_t)bh * 2048 + j] = 1.0f / v;
    }
  }
}

// ---------------------------------------------------------------------------
// Scale V^T rows by Linv along n:  VT[bh][c][n] *= Linv[bh][n]
// 4,194,304 elems / 8 per thread / 256 per block = 2048 blocks (exact).
// ---------------------------------------------------------------------------
__global__ __launch_bounds__(256) void k_scale_v(
    u16* __restrict__ wsu, const float* __restrict__ Linv)
{
  u16* VT = wsu + OFF_VT;
  const size_t vid = (size_t)blockIdx.x * 256 + threadIdx.x;  // 0..524287
  if (vid * 8 >= VT_ELEMS) return;           // safety: never touch past VT
  const size_t base = vid * 8;
  const int n8 = (int)(vid & 255);
  const int bh = (int)(vid >> 14);
  ushort4 a = *(ushort4*)&VT[base];
  ushort4 b = *(ushort4*)&VT[base + 4];
  const float* Lp = Linv + (size_t)bh * 2048 + n8 * 8;
  a.x = f2bf(bf2f(a.x) * Lp[0]);
  a.y = f2bf(bf2f(a.y) * Lp[1]);
  a.z = f2bf(bf2f(a.z) * Lp[2]);
  a.w = f2bf(bf2f(a.w) * Lp[3]);
  b.x = f2bf(bf2f(b.x) * Lp[4]);
  b.y = f2bf(bf2f(b.y) * Lp[5]);
  b.z = f2bf(bf2f(b.z) * Lp[6]);
  b.w = f2bf(bf2f(b.w) * Lp[7]);
  *(ushort4*)&VT[base] = a;
  *(ushort4*)&VT[base + 4] = b;
}

// ---------------------------------------------------------------------------
// Pass 2 (32x32 swapped, in-register P): AV[i][c] = sum_j exp(S_ij) * V'[j][c]
// ---------------------------------------------------------------------------
__global__ __launch_bounds__(256, 2) void k_pass2(u16* __restrict__ wsu)
{
  const int bid = blockIdx.x;                  // 512
  const int swz = (bid & 7) * 64 + (bid >> 3);
  const int itile = swz & 15, bh = swz >> 4;
  const int i0 = itile * 128;
  const u16* Qh = wsu + OFF_Q_HI + (size_t)bh * 131072;
  const u16* Ql = wsu + OFF_Q_LO + (size_t)bh * 131072;
  const u16* Kh = wsu + OFF_K_HI + (size_t)bh * 131072;
  const u16* Kl = wsu + OFF_K_LO + (size_t)bh * 131072;
  const u16* VT = wsu + OFF_VT   + (size_t)bh * 131072;

  __shared__ __align__(16) u16 lds[2][3][4096];  // [buf][Khi,Klo,V][64][64]

  const int tid = threadIdx.x;
  const int w = tid >> 6, l = tid & 63;
  const int il = l & 31, hi = l >> 5;

  // stationary Q B-frags (col=i, k=d)
  bf16x8 qbh[4], qbl[4];
  {
    const int irow = i0 + w * 32 + il;
    #pragma unroll
    for (int ks = 0; ks < 4; ++ks) {
      const size_t o = (size_t)irow * 64 + ks * 16 + hi * 8;
      qbh[ks] = frag(&Qh[o]);
      qbl[ks] = frag(&Ql[o]);
    }
  }

  auto stage = [&](int buf, int jc) {
    const int j0 = jc * 64;
    #pragma unroll
    for (int it = 0; it < 6; ++it) {
      const int c = tid + it * 256;            // 0..1535
      const int plane = c >> 9, cc = c & 511;
      const int r = cc >> 3, cl = cc & 7;
      const int sw8 = (cl ^ (r & 7)) * 8;
      const u16* src = plane == 0 ? Kh + (size_t)(j0 + r) * 64 + sw8
                     : plane == 1 ? Kl + (size_t)(j0 + r) * 64 + sw8
                                  : VT + (size_t)r * 2048 + j0 + sw8;
      gload16(src, &lds[buf][0][0] + (size_t)c * 8);
    }
  };

  const f32x16 fz16 = {0,0,0,0,0,0,0,0,0,0,0,0,0,0,0,0};
  f32x16 acc[2]; acc[0] = fz16; acc[1] = fz16;

  stage(0, 0);
  __syncthreads();
  int cur = 0;
  for (int jc = 0; jc < 32; ++jc) {
    if (jc < 31) stage(cur ^ 1, jc + 1);
    const u16* Ksh = &lds[cur][0][0];
    const u16* Ksl = &lds[cur][1][0];
    const u16* Vs  = &lds[cur][2][0];
    #pragma unroll
    for (int jt = 0; jt < 2; ++jt) {
      // S^T tile: rows j (reg map), cols i (=il)
      f32x16 s = fz16;
      const int jrow = jt * 32 + il;
      #pragma unroll
      for (int ks = 0; ks < 4; ++ks) {
        const int ch = ((ks * 2 + hi) ^ (jrow & 7)) * 8;
        bf16x8 ka  = frag(&Ksh[jrow * 64 + ch]);
        bf16x8 kl_ = frag(&Ksl[jrow * 64 + ch]);
        s = mfma32(ka,  qbh[ks], s);
        s = mfma32(ka,  qbl[ks], s);
        s = mfma32(kl_, qbh[ks], s);
      }
      // P = exp(S) (V pre-scaled by Linv), packed to bf16 pairs
      float p[16];
      #pragma unroll
      for (int r = 0; r < 16; ++r) p[r] = __expf(s[r]);
      // own words: j = (r&3)+8*(r>>2)+4*hi
      u32 W01   = pkbf(p[0],  p[1]),  W23   = pkbf(p[2],  p[3]);
      u32 W89   = pkbf(p[4],  p[5]),  W1011 = pkbf(p[6],  p[7]);
      u32 W1617 = pkbf(p[8],  p[9]),  W1819 = pkbf(p[10], p[11]);
      u32 W2425 = pkbf(p[12], p[13]), W2627 = pkbf(p[14], p[15]);
      // cross-half exchange: partner lane (l^32) has same i, other j-quads
      const u32 W01p   = __shfl_xor(W01,   32);
      const u32 W23p   = __shfl_xor(W23,   32);
      const u32 W89p   = __shfl_xor(W89,   32);
      const u32 W1011p = __shfl_xor(W1011, 32);
      const u32 W1617p = __shfl_xor(W1617, 32);
      const u32 W1819p = __shfl_xor(W1819, 32);
      const u32 W2425p = __shfl_xor(W2425, 32);
      const u32 W2627p = __shfl_xor(W2627, 32);
      // A-frag k-order: lane needs j = kbase + hi*8 + e
      u32x4 pw0 = { hi ? W89p   : W01,   hi ? W1011p : W23,
                    hi ? W89    : W01p,  hi ? W1011  : W23p };   // j 0..15
      u32x4 pw1 = { hi ? W2425p : W1617, hi ? W2627p : W1819,
                    hi ? W2425  : W1617p, hi ? W2627 : W1819p }; // j 16..31
      bf16x8 pa0 = __builtin_bit_cast(bf16x8, pw0);
      bf16x8 pa1 = __builtin_bit_cast(bf16x8, pw1);
      // PV: acc[cb] += P(32i x 32j as A) . V'(B col=c, k=j)
      #pragma unroll
      for (int cb = 0; cb < 2; ++cb) {
        const int crow = cb * 32 + il;
        const int c0 = ((jt * 4 + 0 + hi) ^ (crow & 7)) * 8;   // j 0..15
        const int c1 = ((jt * 4 + 2 + hi) ^ (crow & 7)) * 8;   // j 16..31
        bf16x8 vb0 = frag(&Vs[crow * 64 + c0]);
        bf16x8 vb1 = frag(&Vs[crow * 64 + c1]);
        acc[cb] = mfma32(pa0, vb0, acc[cb]);
        acc[cb] = mfma32(pa1, vb1, acc[cb]);
      }
    }
    __syncthreads();
    cur ^= 1;
  }

  u16* AVh = wsu + OFF_AV_HI;
  u16* AVl = wsu + OFF_AV_LO;
  #pragma unroll
  for (int cb = 0; cb < 2; ++cb)
    #pragma unroll
    for (int r = 0; r < 16; ++r) {
      const int iloc = (r & 3) + 8 * (r >> 2) + 4 * hi;
      const int g = i0 + w * 32 + iloc;
      const int c = cb * 32 + il;
      const float v = acc[cb][r];
      const size_t o = ((size_t)bh * 2048 + g) * 64 + c;
      const u16 hb = f2bf(v);
      AVh[o] = hb;
      AVl[o] = f2bf(v - bf2f(hb));
    }
}

// ---------------------------------------------------------------------------
// Output projection: Out = (AVhi+AVlo)[4096][1024] . WO  (2-term split)
// ---------------------------------------------------------------------------
__global__ __launch_bounds__(256, 2) void k_outproj(
    const u16* __restrict__ wsu, float* __restrict__ Out)
{
  const int bx = blockIdx.x;                 // 256 = gm(32) * dn(8)
  const int gm = bx >> 3, dn = bx & 7;
  const int g0 = gm * 128, d0 = dn * 128;
  const u16* AVh = wsu + OFF_AV_HI;
  const u16* AVl = wsu + OFF_AV_LO;
  const u16* WOT = wsu + OFF_WOT;

  __shared__ __align__(16) u16 Ah[128][72], Al[128][72], Bs[128][72];

  const int tid = threadIdx.x;
  const int w = tid >> 6, l = tid & 63, lr = l & 15, lg = l >> 4;
  const int wm = w >> 1, wn = w & 1;

  const f32x4 fz = {0.f, 0.f, 0.f, 0.f};
  f32x4 acc[4][4];
  for (int i = 0; i < 4; ++i) for (int j = 0; j < 4; ++j) acc[i][j] = fz;

  for (int kt = 0; kt < 16; ++kt) {
    const int c0 = kt * 64;
    __syncthreads();
    for (int s = 0; s < 12; ++s) {
      int idx = tid + s * 256;
      int sel = idx >> 10, i2 = idx & 1023;
      int r = i2 >> 3, c8 = (i2 & 7) * 8;
      const u16* src = sel == 0 ? AVh + (size_t)(g0 + r) * 1024 + c0 + c8
                     : sel == 1 ? AVl + (size_t)(g0 + r) * 1024 + c0 + c8
                                : WOT + (size_t)(d0 + r) * 1024 + c0 + c8;
      u16* dst = sel == 0 ? &Ah[r][c8] : sel == 1 ? &Al[r][c8] : &Bs[r][c8];
      *(uint4*)dst = *(const uint4*)src;
    }
    __syncthreads();
    #pragma unroll
    for (int ks = 0; ks < 2; ++ks) {
      bf16x8 ah[4], al[4];
      #pragma unroll
      for (int mf = 0; mf < 4; ++mf) {
        ah[mf] = frag(&Ah[wm * 64 + mf * 16 + lr][ks * 32 + lg * 8]);
        al[mf] = frag(&Al[wm * 64 + mf * 16 + lr][ks * 32 + lg * 8]);
      }
      #pragma unroll
      for (int nf = 0; nf < 4; ++nf) {
        bf16x8 bfv = frag(&Bs[wn * 64 + nf * 16 + lr][ks * 32 + lg * 8]);
        #pragma unroll
        for (int mf = 0; mf < 4; ++mf) {
          acc[mf][nf] = mfma16(ah[mf], bfv, acc[mf][nf]);
          acc[mf][nf] = mfma16(al[mf], bfv, acc[mf][nf]);
        }
      }
    }
  }
  #pragma unroll
  for (int mf = 0; mf < 4; ++mf)
    #pragma unroll
    for (int nf = 0; nf < 4; ++nf)
      #pragma unroll
      for (int r = 0; r < 4; ++r) {
        const int g = g0 + wm * 64 + mf * 16 + lg * 4 + r;
        const int d = d0 + wn * 64 + nf * 16 + lr;
        Out[(size_t)g * 1024 + d] = acc[mf][nf][r];
      }
}

} // anonymous namespace

extern "C" void kernel_launch(void* const* d_in, const int* in_sizes, int n_in,
                              void* d_out, int out_size, void* d_ws, size_t ws_size,
                              hipStream_t stream) {
  const float* X  = (const float*)d_in[0];
  const float* Wq = (const float*)d_in[1];
  const float* Wk = (const float*)d_in[2];
  const float* Wv = (const float*)d_in[3];
  const float* Wo = (const float*)d_in[4];
  float* out = (float*)d_out;
  u16* wsu = (u16*)d_ws;
  float* Linv = (float*)(wsu + OFF_LINV);

  k_prep_x   <<<2048, 256, 0, stream>>>(X, wsu);
  k_prep_wo  <<<256,  256, 0, stream>>>(Wo, wsu);
  k_prep_w   <<<256,  256, 0, stream>>>(Wq, wsu);
  k_projg<0> <<<512,  256, 0, stream>>>(wsu);
  k_prep_w   <<<256,  256, 0, stream>>>(Wk, wsu);
  k_projg<1> <<<512,  256, 0, stream>>>(wsu);
  k_prep_w   <<<256,  256, 0, stream>>>(Wv, wsu);
  k_projg<2> <<<512,  256, 0, stream>>>(wsu);
  k_pass1    <<<512,  256, 0, stream>>>(wsu, Linv);
  k_scale_v  <<<2048, 256, 0, stream>>>(wsu, Linv);   // FIX: was 4096 (2x OOB)
  k_pass2    <<<512,  256, 0, stream>>>(wsu);
  k_outproj  <<<256,  256, 0, stream>>>(wsu, out);
}

// Round 6
// 273.934 us; speedup vs baseline: 1.0903x; 1.0796x over previous
//
#include <hip/hip_runtime.h>
#include <math.h>

namespace {

typedef unsigned short u16;
typedef unsigned int   u32;
typedef __bf16 bf16x8 __attribute__((ext_vector_type(8)));
typedef float  f32x4  __attribute__((ext_vector_type(4)));
typedef float  f32x16 __attribute__((ext_vector_type(16)));
typedef u32    u32x4  __attribute__((ext_vector_type(4)));

// ---- workspace layout (u16 element offsets) --------------------------------
constexpr size_t OFF_XH     = 0;          // [4096][1024] bf16 hi of X
constexpr size_t OFF_WTS_HI = 8388608;    // [1024 j=h*64+k'][1024 d] (per-qkv slot)
constexpr size_t OFF_WTS_LO = 9437184;
constexpr size_t OFF_Q_HI   = 10485760;   // [32 bh][2048][64]
constexpr size_t OFF_Q_LO   = 14680064;
constexpr size_t OFF_K_HI   = 18874368;
constexpr size_t OFF_VT     = 27262976;   // [32 bh][64][2048]
constexpr size_t OFF_WOT    = 31457280;   // [1024 d'][1024 c]
constexpr size_t OFF_LINV   = 32505856;   // f32[65536] raw column sums l_j
constexpr size_t OFF_AV_HI  = 0;          // aliases XH (dead after proj)
// end = 65,273,856 B (< 67.6 MB proven safe in R1)

constexpr size_t VT_ELEMS = (size_t)32 * 64 * 2048;       // 4,194,304

__device__ __forceinline__ u16 f2bf(float x) {            // RNE fp32 -> bf16
  union { float f; unsigned u; } v; v.f = x;
  unsigned r = v.u + 0x7FFFu + ((v.u >> 16) & 1u);
  return (u16)(r >> 16);
}
__device__ __forceinline__ float bf2f(u16 b) {
  union { unsigned u; float f; } v; v.u = (unsigned)b << 16; return v.f;
}
__device__ __forceinline__ bf16x8 frag(const u16* p) {
  return *reinterpret_cast<const bf16x8*>(p);
}
__device__ __forceinline__ f32x4 mfma16(bf16x8 a, bf16x8 b, f32x4 c) {
  return __builtin_amdgcn_mfma_f32_16x16x32_bf16(a, b, c, 0, 0, 0);
}
__device__ __forceinline__ f32x16 mfma32(bf16x8 a, bf16x8 b, f32x16 c) {
  return __builtin_amdgcn_mfma_f32_32x32x16_bf16(a, b, c, 0, 0, 0);
}
__device__ __forceinline__ void gload16(const void* g, void* l) {
  __builtin_amdgcn_global_load_lds(
      (const __attribute__((address_space(1))) u32*)g,
      (__attribute__((address_space(3))) u32*)l, 16, 0, 0);
}
// packed RNE f32x2 -> bf16x2 (lo in low half) — 1 instr vs ~10 VALU
__device__ __forceinline__ u32 cvtpk(float lo, float hi) {
  u32 r;
  asm("v_cvt_pk_bf16_f32 %0, %1, %2" : "=v"(r) : "v"(lo), "v"(hi));
  return r;
}
// swap: a.lanes[32:63] <-> b.lanes[0:31]
__device__ __forceinline__ void pswap(u32& a, u32& b) {
  asm("v_permlane32_swap_b32 %0, %1" : "+v"(a), "+v"(b));
}

// ---------------------------------------------------------------------------
// Prep X: X f32 -> Xh bf16 (hi only; 2-term proj drops X_lo)
// ---------------------------------------------------------------------------
__global__ __launch_bounds__(256) void k_prep_x(
    const float* __restrict__ X, u16* __restrict__ wsu)
{
  u16* Xh = wsu + OFF_XH;
  const size_t i = ((size_t)blockIdx.x * 256 + threadIdx.x) * 4;  // 4096 blocks exact
  const float4 v = *(const float4*)&X[i];
  ushort4 hh;
  hh.x = f2bf(v.x); hh.y = f2bf(v.y); hh.z = f2bf(v.z); hh.w = f2bf(v.w);
  *(ushort4*)&Xh[i] = hh;
}

// Zero the column-sum accumulator (re-zeroed every launch; atomicAdd target)
__global__ __launch_bounds__(256) void k_zero_l(float* __restrict__ L)
{
  const size_t i = ((size_t)blockIdx.x * 256 + threadIdx.x) * 4;  // 64 blocks
  *(float4*)&L[i] = make_float4(0.f, 0.f, 0.f, 0.f);
}

// ---------------------------------------------------------------------------
// Prep one W: transpose + hi/lo split W[h][d][k'] -> WTS[j=h*64+k'][d]
// ---------------------------------------------------------------------------
__global__ __launch_bounds__(256) void k_prep_w(
    const float* __restrict__ W, u16* __restrict__ wsu)
{
  const int bx = blockIdx.x;                 // 256 = h(16) * dchunk(16)
  const int h = bx >> 4, dc = bx & 15;
  const int d0 = dc * 64;
  __shared__ float T[64][65];
  const int tid = threadIdx.x;
  for (int l = 0; l < 16; ++l) {
    int idx = tid + l * 256; int r = idx >> 6, c = idx & 63;  // r=d, c=k'
    T[r][c] = W[((size_t)h * 1024 + d0 + r) * 64 + c];
  }
  __syncthreads();
  u16* Wh = wsu + OFF_WTS_HI;
  u16* Wl = wsu + OFF_WTS_LO;
  for (int l = 0; l < 16; ++l) {
    int idx = tid + l * 256; int r = idx >> 6, c = idx & 63;  // r=k', c=d
    float v = T[c][r];
    u16 hi = f2bf(v);
    size_t o = (size_t)(h * 64 + r) * 1024 + d0 + c;
    Wh[o] = hi;
    Wl[o] = f2bf(v - bf2f(hi));
  }
}

// Prep: transpose W_O[c][d'] -> WOT[d'][c]
__global__ __launch_bounds__(256) void k_prep_wo(
    const float* __restrict__ Wo, u16* __restrict__ wsu)
{
  const int bx = blockIdx.x;
  const int c0 = (bx >> 4) * 64, dd0 = (bx & 15) * 64;
  __shared__ float T[64][65];
  const int tid = threadIdx.x;
  for (int l = 0; l < 16; ++l) {
    int idx = tid + l * 256; int r = idx >> 6, c = idx & 63;
    T[r][c] = Wo[(size_t)(c0 + r) * 1024 + dd0 + c];
  }
  __syncthreads();
  u16* WOT = wsu + OFF_WOT;
  for (int l = 0; l < 16; ++l) {
    int idx = tid + l * 256; int r = idx >> 6, c = idx & 63;
    WOT[(size_t)(dd0 + r) * 1024 + c0 + c] = f2bf(T[c][r]);
  }
}

// ---------------------------------------------------------------------------
// Projection GEMM (per qkv): C[4096][1024] = Xh . (Wh+Wl), 2-term split.
// MODE 0: Q (hi/lo store)  1: K (hi only)  2: V (transposed single-bf16).
// ---------------------------------------------------------------------------
template <int MODE>
__global__ __launch_bounds__(256, 2) void k_projg(u16* __restrict__ wsu)
{
  const int bid = blockIdx.x;                // 512
  const int s  = (bid & 7) * 64 + (bid >> 3);
  const int mt = s >> 4, h = s & 15;
  const int gm0 = mt * 128;
  const int j0 = h * 64;

  const u16* XH = wsu + OFF_XH;
  const u16* WH = wsu + OFF_WTS_HI;
  const u16* WL = wsu + OFF_WTS_LO;

  __shared__ __align__(16) u16 lds[16384];   // Ah[128][64] Bh[64][64] Bl
  u16* Ah = lds;
  u16* Bh = lds + 8192;
  u16* Bl = lds + 12288;

  const int tid = threadIdx.x;
  const int w = tid >> 6, l = tid & 63, lr = l & 15, lg = l >> 4;
  const int wm = w >> 1, wn = w & 1;

  const f32x4 fz = {0.f, 0.f, 0.f, 0.f};
  f32x4 acc[4][2];
  for (int i = 0; i < 4; ++i) for (int j = 0; j < 2; ++j) acc[i][j] = fz;

  for (int kt = 0; kt < 16; ++kt) {
    const int d0 = kt * 64;
    __syncthreads();
    #pragma unroll
    for (int it = 0; it < 8; ++it) {
      const int c = tid + it * 256;          // 0..2047 16B chunks
      const u16* src;
      if (c < 1024) {                        // A plane
        const int r = c >> 3, col8 = (c & 7) * 8;
        src = XH + (size_t)(gm0 + r) * 1024 + d0 + col8;
      } else {                               // B planes
        const int cc = c - 1024;
        const int plane = cc >> 9, c2 = cc & 511;
        const int r = c2 >> 3, col8 = (c2 & 7) * 8;
        src = (plane ? WL : WH) + (size_t)(j0 + r) * 1024 + d0 + col8;
      }
      gload16(src, lds + (size_t)c * 8);
    }
    __syncthreads();

    #pragma unroll
    for (int ks = 0; ks < 2; ++ks) {
      bf16x8 a_h[4], b_h[2], b_l[2];
      #pragma unroll
      for (int mf = 0; mf < 4; ++mf) {
        const int row = wm * 64 + mf * 16 + lr;
        a_h[mf] = frag(Ah + row * 64 + ks * 32 + lg * 8);
      }
      #pragma unroll
      for (int nf = 0; nf < 2; ++nf) {
        const int row = wn * 32 + nf * 16 + lr;
        b_h[nf] = frag(Bh + row * 64 + ks * 32 + lg * 8);
        b_l[nf] = frag(Bl + row * 64 + ks * 32 + lg * 8);
      }
      #pragma unroll
      for (int nf = 0; nf < 2; ++nf)
        #pragma unroll
        for (int mf = 0; mf < 4; ++mf) {
          acc[mf][nf] = mfma16(a_h[mf], b_h[nf], acc[mf][nf]);
          acc[mf][nf] = mfma16(a_h[mf], b_l[nf], acc[mf][nf]);
        }
    }
  }

  if (MODE == 0) {       // Q: hi/lo planes [bh][n][64]
    u16* Ph = wsu + OFF_Q_HI;
    u16* Pl = wsu + OFF_Q_LO;
    #pragma unroll
    for (int mf = 0; mf < 4; ++mf)
      #pragma unroll
      for (int nf = 0; nf < 2; ++nf)
        #pragma unroll
        for (int r = 0; r < 4; ++r) {
          const float v = acc[mf][nf][r];
          const int gn = gm0 + wm * 64 + mf * 16 + lg * 4 + r;
          const int b = gn >> 11, n = gn & 2047;
          const int kp = wn * 32 + nf * 16 + lr;
          const size_t o = ((size_t)(b * 16 + h) * 2048 + n) * 64 + kp;
          const u16 hi = f2bf(v);
          Ph[o] = hi;
          Pl[o] = f2bf(v - bf2f(hi));
        }
  } else if (MODE == 1) { // K: hi only (2-term S drops K_lo)
    u16* Ph = wsu + OFF_K_HI;
    #pragma unroll
    for (int mf = 0; mf < 4; ++mf)
      #pragma unroll
      for (int nf = 0; nf < 2; ++nf)
        #pragma unroll
        for (int r = 0; r < 4; ++r) {
          const int gn = gm0 + wm * 64 + mf * 16 + lg * 4 + r;
          const int b = gn >> 11, n = gn & 2047;
          const int kp = wn * 32 + nf * 16 + lr;
          Ph[((size_t)(b * 16 + h) * 2048 + n) * 64 + kp] = f2bf(acc[mf][nf][r]);
        }
  } else {               // V: transposed store VT[bh][k'][n], 4n packed
    u16* VT = wsu + OFF_VT;
    #pragma unroll
    for (int mf = 0; mf < 4; ++mf)
      #pragma unroll
      for (int nf = 0; nf < 2; ++nf) {
        const int gn = gm0 + wm * 64 + mf * 16 + lg * 4;
        const int b = gn >> 11, n = gn & 2047;
        const int kp = wn * 32 + nf * 16 + lr;
        ushort4 p;
        p.x = f2bf(acc[mf][nf][0]); p.y = f2bf(acc[mf][nf][1]);
        p.z = f2bf(acc[mf][nf][2]); p.w = f2bf(acc[mf][nf][3]);
        *(ushort4*)&VT[((size_t)(b * 16 + h) * 64 + kp) * 2048 + n] = p;
      }
  }
}

// ---------------------------------------------------------------------------
// Pass 1 (i-split x4): partial l_j = sum_{i in slice} exp(S_ij), atomicAdd.
// Grid 2048 (~20 waves/CU). A=Kh rows (stationary), B=Q hi/lo streamed.
// ---------------------------------------------------------------------------
__global__ __launch_bounds__(256, 2) void k_pass1(
    u16* __restrict__ wsu, float* __restrict__ L)
{
  const int bid = blockIdx.x;                    // 2048
  const int swz = (bid & 7) * 256 + (bid >> 3);  // same-bh blocks share an XCD
  const int bh = swz >> 6;
  const int jtile = (swz >> 2) & 15;
  const int isl = swz & 3;
  const int j0 = jtile * 128;
  const u16* Qh = wsu + OFF_Q_HI + (size_t)bh * 131072;
  const u16* Ql = wsu + OFF_Q_LO + (size_t)bh * 131072;
  const u16* Kh = wsu + OFF_K_HI + (size_t)bh * 131072;

  __shared__ __align__(16) u16 lds[2][2][4096];   // [buf][Qhi,Qlo][64][64]

  const int tid = threadIdx.x;
  const int w = tid >> 6, l = tid & 63;
  const int il = l & 31, hi = l >> 5;

  bf16x8 kah[4];                                 // stationary K A-frags
  {
    const int jrow = j0 + w * 32 + il;
    #pragma unroll
    for (int ks = 0; ks < 4; ++ks)
      kah[ks] = frag(&Kh[(size_t)jrow * 64 + ks * 16 + hi * 8]);
  }

  auto stage = [&](int buf, int ic) {
    const int i0 = ic * 64;
    #pragma unroll
    for (int it = 0; it < 4; ++it) {
      const int c = tid + it * 256;              // 0..1023
      const int plane = c >> 9, cc = c & 511;
      const int r = cc >> 3, cl = cc & 7;
      const int sw8 = (cl ^ (r & 7)) * 8;        // inverse-swizzled source
      const u16* src = (plane ? Ql : Qh) + (size_t)(i0 + r) * 64 + sw8;
      gload16(src, &lds[buf][0][0] + (size_t)c * 8);
    }
  };

  const f32x16 fz16 = {0,0,0,0,0,0,0,0,0,0,0,0,0,0,0,0};
  float lsum[16] = {};
  const int icbase = isl * 8;

  stage(0, icbase);
  __syncthreads();
  int cur = 0;
  for (int ii = 0; ii < 8; ++ii) {
    if (ii < 7) stage(cur ^ 1, icbase + ii + 1);
    const u16* Qsh = &lds[cur][0][0];
    const u16* Qsl = &lds[cur][1][0];
    #pragma unroll
    for (int it2 = 0; it2 < 2; ++it2) {
      f32x16 s = fz16;
      const int qrow = it2 * 32 + il;
      #pragma unroll
      for (int ks = 0; ks < 4; ++ks) {
        const int ch = ((ks * 2 + hi) ^ (qrow & 7)) * 8;   // swizzled read
        s = mfma32(kah[ks], frag(&Qsh[qrow * 64 + ch]), s);
        s = mfma32(kah[ks], frag(&Qsl[qrow * 64 + ch]), s);
      }
      #pragma unroll
      for (int r = 0; r < 16; ++r) lsum[r] += __expf(s[r]);
    }
    __syncthreads();
    cur ^= 1;
  }

  #pragma unroll
  for (int r = 0; r < 16; ++r) {
    float v = lsum[r];
    v += __shfl_xor(v, 1);  v += __shfl_xor(v, 2);
    v += __shfl_xor(v, 4);  v += __shfl_xor(v, 8);
    v += __shfl_xor(v, 16);
    if (il == 0) {
      const int j = j0 + w * 32 + (r & 3) + 8 * (r >> 2) + 4 * hi;
      atomicAdd(&L[(size_t)bh * 2048 + j], v);
    }
  }
}

// ---------------------------------------------------------------------------
// Scale V^T by 1/l along n:  VT[bh][c][n] *= rcp(L[bh][n])
// ---------------------------------------------------------------------------
__global__ __launch_bounds__(256) void k_scale_v(
    u16* __restrict__ wsu, const float* __restrict__ L)
{
  u16* VT = wsu + OFF_VT;
  const size_t vid = (size_t)blockIdx.x * 256 + threadIdx.x;  // 0..524287
  if (vid * 8 >= VT_ELEMS) return;
  const size_t base = vid * 8;
  const int n8 = (int)(vid & 255);
  const int bh = (int)(vid >> 14);
  ushort4 a = *(ushort4*)&VT[base];
  ushort4 b = *(ushort4*)&VT[base + 4];
  const float* Lp = L + (size_t)bh * 2048 + n8 * 8;
  a.x = f2bf(bf2f(a.x) * __builtin_amdgcn_rcpf(Lp[0]));
  a.y = f2bf(bf2f(a.y) * __builtin_amdgcn_rcpf(Lp[1]));
  a.z = f2bf(bf2f(a.z) * __builtin_amdgcn_rcpf(Lp[2]));
  a.w = f2bf(bf2f(a.w) * __builtin_amdgcn_rcpf(Lp[3]));
  b.x = f2bf(bf2f(b.x) * __builtin_amdgcn_rcpf(Lp[4]));
  b.y = f2bf(bf2f(b.y) * __builtin_amdgcn_rcpf(Lp[5]));
  b.z = f2bf(bf2f(b.z) * __builtin_amdgcn_rcpf(Lp[6]));
  b.w = f2bf(bf2f(b.w) * __builtin_amdgcn_rcpf(Lp[7]));
  *(ushort4*)&VT[base] = a;
  *(ushort4*)&VT[base + 4] = b;
}

// ---------------------------------------------------------------------------
// Pass 2 (32x32 swapped, in-register P): AV[i][c] = sum_j exp(S_ij) * V'[j][c]
// 2-term S (Kh only). P repack via v_cvt_pk_bf16_f32 + v_permlane32_swap_b32.
// ---------------------------------------------------------------------------
__global__ __launch_bounds__(256, 2) void k_pass2(u16* __restrict__ wsu)
{
  const int bid = blockIdx.x;                  // 512
  const int swz = (bid & 7) * 64 + (bid >> 3);
  const int itile = swz & 15, bh = swz >> 4;
  const int i0 = itile * 128;
  const u16* Qh = wsu + OFF_Q_HI + (size_t)bh * 131072;
  const u16* Ql = wsu + OFF_Q_LO + (size_t)bh * 131072;
  const u16* Kh = wsu + OFF_K_HI + (size_t)bh * 131072;
  const u16* VT = wsu + OFF_VT   + (size_t)bh * 131072;

  __shared__ __align__(16) u16 lds[2][2][4096];  // [buf][Kh,V][64][64]

  const int tid = threadIdx.x;
  const int w = tid >> 6, l = tid & 63;
  const int il = l & 31, hi = l >> 5;

  bf16x8 qbh[4], qbl[4];                       // stationary Q B-frags
  {
    const int irow = i0 + w * 32 + il;
    #pragma unroll
    for (int ks = 0; ks < 4; ++ks) {
      const size_t o = (size_t)irow * 64 + ks * 16 + hi * 8;
      qbh[ks] = frag(&Qh[o]);
      qbl[ks] = frag(&Ql[o]);
    }
  }

  auto stage = [&](int buf, int jc) {
    const int j0 = jc * 64;
    #pragma unroll
    for (int it = 0; it < 4; ++it) {
      const int c = tid + it * 256;            // 0..1023
      const int plane = c >> 9, cc = c & 511;
      const int r = cc >> 3, cl = cc & 7;
      const int sw8 = (cl ^ (r & 7)) * 8;
      const u16* src = plane == 0 ? Kh + (size_t)(j0 + r) * 64 + sw8
                                  : VT + (size_t)r * 2048 + j0 + sw8;
      gload16(src, &lds[buf][0][0] + (size_t)c * 8);
    }
  };

  const f32x16 fz16 = {0,0,0,0,0,0,0,0,0,0,0,0,0,0,0,0};
  f32x16 acc[2]; acc[0] = fz16; acc[1] = fz16;

  stage(0, 0);
  __syncthreads();
  int cur = 0;
  for (int jc = 0; jc < 32; ++jc) {
    if (jc < 31) stage(cur ^ 1, jc + 1);
    const u16* Ksh = &lds[cur][0][0];
    const u16* Vs  = &lds[cur][1][0];
    #pragma unroll
    for (int jt = 0; jt < 2; ++jt) {
      // S^T tile: rows j (reg map), cols i (=il)
      f32x16 s = fz16;
      const int jrow = jt * 32 + il;
      #pragma unroll
      for (int ks = 0; ks < 4; ++ks) {
        const int ch = ((ks * 2 + hi) ^ (jrow & 7)) * 8;
        bf16x8 ka = frag(&Ksh[jrow * 64 + ch]);
        s = mfma32(ka, qbh[ks], s);
        s = mfma32(ka, qbl[ks], s);
      }
      // P = exp(S) (V pre-scaled by 1/l); pack + cross-half exchange
      float p[16];
      #pragma unroll
      for (int r = 0; r < 16; ++r) p[r] = __expf(s[r]);
      u32 a0 = cvtpk(p[0],  p[1]),  b0 = cvtpk(p[4],  p[5]);
      u32 a1 = cvtpk(p[2],  p[3]),  b1 = cvtpk(p[6],  p[7]);
      u32 a2 = cvtpk(p[8],  p[9]),  b2 = cvtpk(p[12], p[13]);
      u32 a3 = cvtpk(p[10], p[11]), b3 = cvtpk(p[14], p[15]);
      pswap(a0, b0); pswap(a1, b1); pswap(a2, b2); pswap(a3, b3);
      u32x4 pw0 = {a0, a1, b0, b1};            // k = j 0..15 of this jt
      u32x4 pw1 = {a2, a3, b2, b3};            // k = j 16..31
      bf16x8 pa0 = __builtin_bit_cast(bf16x8, pw0);
      bf16x8 pa1 = __builtin_bit_cast(bf16x8, pw1);
      // PV: acc[cb] += P(A: row=i, k=j) . V'(B: col=c, k=j)
      #pragma unroll
      for (int cb = 0; cb < 2; ++cb) {
        const int crow = cb * 32 + il;
        const int c0 = ((jt * 4 + 0 + hi) ^ (crow & 7)) * 8;
        const int c1 = ((jt * 4 + 2 + hi) ^ (crow & 7)) * 8;
        bf16x8 vb0 = frag(&Vs[crow * 64 + c0]);
        bf16x8 vb1 = frag(&Vs[crow * 64 + c1]);
        acc[cb] = mfma32(pa0, vb0, acc[cb]);
        acc[cb] = mfma32(pa1, vb1, acc[cb]);
      }
    }
    __syncthreads();
    cur ^= 1;
  }

  u16* AVh = wsu + OFF_AV_HI;                  // hi only (1-term outproj)
  #pragma unroll
  for (int cb = 0; cb < 2; ++cb)
    #pragma unroll
    for (int r = 0; r < 16; ++r) {
      const int iloc = (r & 3) + 8 * (r >> 2) + 4 * hi;
      const int g = i0 + w * 32 + iloc;
      const int c = cb * 32 + il;
      AVh[((size_t)bh * 2048 + g) * 64 + c] = f2bf(acc[cb][r]);
    }
}

// ---------------------------------------------------------------------------
// Output projection: Out = AVh[4096][1024] . WO   (1-term)
// ---------------------------------------------------------------------------
__global__ __launch_bounds__(256, 2) void k_outproj(
    const u16* __restrict__ wsu, float* __restrict__ Out)
{
  const int bx = blockIdx.x;                 // 256 = gm(32) * dn(8)
  const int gm = bx >> 3, dn = bx & 7;
  const int g0 = gm * 128, d0 = dn * 128;
  const u16* AVh = wsu + OFF_AV_HI;
  const u16* WOT = wsu + OFF_WOT;

  __shared__ __align__(16) u16 Ah[128][72], Bs[128][72];

  const int tid = threadIdx.x;
  const int w = tid >> 6, l = tid & 63, lr = l & 15, lg = l >> 4;
  const int wm = w >> 1, wn = w & 1;

  const f32x4 fz = {0.f, 0.f, 0.f, 0.f};
  f32x4 acc[4][4];
  for (int i = 0; i < 4; ++i) for (int j = 0; j < 4; ++j) acc[i][j] = fz;

  for (int kt = 0; kt < 16; ++kt) {
    const int c0 = kt * 64;
    __syncthreads();
    for (int s = 0; s < 8; ++s) {            // 2 planes x 1024 uint4
      int idx = tid + s * 256;
      int sel = idx >> 10, i2 = idx & 1023;
      int r = i2 >> 3, c8 = (i2 & 7) * 8;
      const u16* src = sel == 0 ? AVh + (size_t)(g0 + r) * 1024 + c0 + c8
                                : WOT + (size_t)(d0 + r) * 1024 + c0 + c8;
      u16* dst = sel == 0 ? &Ah[r][c8] : &Bs[r][c8];
      *(uint4*)dst = *(const uint4*)src;
    }
    __syncthreads();
    #pragma unroll
    for (int ks = 0; ks < 2; ++ks) {
      bf16x8 ah[4];
      #pragma unroll
      for (int mf = 0; mf < 4; ++mf)
        ah[mf] = frag(&Ah[wm * 64 + mf * 16 + lr][ks * 32 + lg * 8]);
      #pragma unroll
      for (int nf = 0; nf < 4; ++nf) {
        bf16x8 bfv = frag(&Bs[wn * 64 + nf * 16 + lr][ks * 32 + lg * 8]);
        #pragma unroll
        for (int mf = 0; mf < 4; ++mf)
          acc[mf][nf] = mfma16(ah[mf], bfv, acc[mf][nf]);
      }
    }
  }
  #pragma unroll
  for (int mf = 0; mf < 4; ++mf)
    #pragma unroll
    for (int nf = 0; nf < 4; ++nf)
      #pragma unroll
      for (int r = 0; r < 4; ++r) {
        const int g = g0 + wm * 64 + mf * 16 + lg * 4 + r;
        const int d = d0 + wn * 64 + nf * 16 + lr;
        Out[(size_t)g * 1024 + d] = acc[mf][nf][r];
      }
}

} // anonymous namespace

extern "C" void kernel_launch(void* const* d_in, const int* in_sizes, int n_in,
                              void* d_out, int out_size, void* d_ws, size_t ws_size,
                              hipStream_t stream) {
  const float* X  = (const float*)d_in[0];
  const float* Wq = (const float*)d_in[1];
  const float* Wk = (const float*)d_in[2];
  const float* Wv = (const float*)d_in[3];
  const float* Wo = (const float*)d_in[4];
  float* out = (float*)d_out;
  u16* wsu = (u16*)d_ws;
  float* L = (float*)(wsu + OFF_LINV);

  k_prep_x   <<<4096, 256, 0, stream>>>(X, wsu);
  k_zero_l   <<<64,   256, 0, stream>>>(L);
  k_prep_wo  <<<256,  256, 0, stream>>>(Wo, wsu);
  k_prep_w   <<<256,  256, 0, stream>>>(Wq, wsu);
  k_projg<0> <<<512,  256, 0, stream>>>(wsu);
  k_prep_w   <<<256,  256, 0, stream>>>(Wk, wsu);
  k_projg<1> <<<512,  256, 0, stream>>>(wsu);
  k_prep_w   <<<256,  256, 0, stream>>>(Wv, wsu);
  k_projg<2> <<<512,  256, 0, stream>>>(wsu);
  k_pass1    <<<2048, 256, 0, stream>>>(wsu, L);
  k_scale_v  <<<2048, 256, 0, stream>>>(wsu, L);
  k_pass2    <<<512,  256, 0, stream>>>(wsu);
  k_outproj  <<<256,  256, 0, stream>>>(wsu, out);
}

// Round 9
// 244.203 us; speedup vs baseline: 1.2231x; 1.1217x over previous
//
#include <hip/hip_runtime.h>
#include <math.h>

namespace {

typedef unsigned short u16;
typedef unsigned int   u32;
typedef __bf16 bf16x8 __attribute__((ext_vector_type(8)));
typedef float  f32x4  __attribute__((ext_vector_type(4)));
typedef float  f32x16 __attribute__((ext_vector_type(16)));
typedef u32    u32x4  __attribute__((ext_vector_type(4)));

// ---- workspace layout (u16 element offsets) --------------------------------
constexpr size_t OFF_XH  = 0;          // [4096][1024] bf16 hi of X (dead after proj)
constexpr size_t OFF_WH  = 4194304;    // [3072 j=qkv*1024+h*64+k'][1024 d] hi
constexpr size_t OFF_WL  = 7340032;    //                                   lo
constexpr size_t OFF_QH  = 10485760;   // [32 bh][2048][64]
constexpr size_t OFF_QL  = 14680064;   // [32 bh][2048][64]
constexpr size_t OFF_KH  = 18874368;   // [32 bh][2048][64]
constexpr size_t OFF_VT  = 23068672;   // [32 bh][64][2048]
constexpr size_t OFF_WOT = 27262976;   // [1024 d'][1024 c]
constexpr size_t OFF_L   = 28311552;   // f32[65536] raw column sums (131072 u16)
constexpr size_t OFF_AVH = 0;          // aliases XH (dead after proj)
// end = 28,442,624 u16 = 56.9 MB  (< 65.3 MB proven safe)

constexpr size_t VT_ELEMS = (size_t)32 * 64 * 2048;       // 4,194,304

__device__ __forceinline__ u16 f2bf(float x) {            // RNE fp32 -> bf16
  union { float f; unsigned u; } v; v.f = x;
  unsigned r = v.u + 0x7FFFu + ((v.u >> 16) & 1u);
  return (u16)(r >> 16);
}
__device__ __forceinline__ float bf2f(u16 b) {
  union { unsigned u; float f; } v; v.u = (unsigned)b << 16; return v.f;
}
__device__ __forceinline__ bf16x8 frag(const u16* p) {
  return *reinterpret_cast<const bf16x8*>(p);
}
__device__ __forceinline__ f32x4 mfma16(bf16x8 a, bf16x8 b, f32x4 c) {
  return __builtin_amdgcn_mfma_f32_16x16x32_bf16(a, b, c, 0, 0, 0);
}
__device__ __forceinline__ f32x16 mfma32(bf16x8 a, bf16x8 b, f32x16 c) {
  return __builtin_amdgcn_mfma_f32_32x32x16_bf16(a, b, c, 0, 0, 0);
}
__device__ __forceinline__ void gload16(const void* g, void* l) {
  __builtin_amdgcn_global_load_lds(
      (const __attribute__((address_space(1))) u32*)g,
      (__attribute__((address_space(3))) u32*)l, 16, 0, 0);
}
__device__ __forceinline__ u32 cvtpk(float lo, float hi) {
  u32 r;
  asm("v_cvt_pk_bf16_f32 %0, %1, %2" : "=v"(r) : "v"(lo), "v"(hi));
  return r;
}
__device__ __forceinline__ void pswap(u32& a, u32& b) {
  asm("v_permlane32_swap_b32 %0, %1" : "+v"(a), "+v"(b));
}

// ---------------------------------------------------------------------------
// Prep X: X f32 -> Xh bf16 (hi only)   [round-6 verbatim]
// ---------------------------------------------------------------------------
__global__ __launch_bounds__(256) void k_prep_x(
    const float* __restrict__ X, u16* __restrict__ wsu)
{
  u16* Xh = wsu + OFF_XH;
  const size_t i = ((size_t)blockIdx.x * 256 + threadIdx.x) * 4;  // 4096 blocks
  const float4 v = *(const float4*)&X[i];
  ushort4 hh;
  hh.x = f2bf(v.x); hh.y = f2bf(v.y); hh.z = f2bf(v.z); hh.w = f2bf(v.w);
  *(ushort4*)&Xh[i] = hh;
}

// Zero the column-sum accumulator (re-zeroed every launch)  [round-6 verbatim]
__global__ __launch_bounds__(256) void k_zero_l(float* __restrict__ L)
{
  const size_t i = ((size_t)blockIdx.x * 256 + threadIdx.x) * 4;  // 64 blocks
  *(float4*)&L[i] = make_float4(0.f, 0.f, 0.f, 0.f);
}

// ---------------------------------------------------------------------------
// Prep all W: transpose + hi/lo split W[qkv][h][d][k'] -> WALL[j][d]
// ---------------------------------------------------------------------------
__global__ __launch_bounds__(256) void k_prep_wall(
    const float* __restrict__ Wq, const float* __restrict__ Wk,
    const float* __restrict__ Wv, u16* __restrict__ wsu)
{
  const int bx = blockIdx.x;                 // 768 = qkv(3)*h(16)*dchunk(16)
  const int qkv = bx >> 8, h = (bx >> 4) & 15, dc = bx & 15;
  const float* W = qkv == 0 ? Wq : qkv == 1 ? Wk : Wv;
  const int d0 = dc * 64;
  __shared__ float T[64][65];
  const int tid = threadIdx.x;
  for (int l = 0; l < 16; ++l) {
    int idx = tid + l * 256; int r = idx >> 6, c = idx & 63;  // r=d, c=k'
    T[r][c] = W[((size_t)h * 1024 + d0 + r) * 64 + c];
  }
  __syncthreads();
  u16* Wh = wsu + OFF_WH;
  u16* Wl = wsu + OFF_WL;
  for (int l = 0; l < 16; ++l) {
    int idx = tid + l * 256; int r = idx >> 6, c = idx & 63;  // r=k', c=d
    float v = T[c][r];
    u16 hi = f2bf(v);
    size_t o = (size_t)((qkv * 16 + h) * 64 + r) * 1024 + d0 + c;
    Wh[o] = hi;
    Wl[o] = f2bf(v - bf2f(hi));
  }
}

// Prep: transpose W_O[c][d'] -> WOT[d'][c]   [round-6 verbatim]
__global__ __launch_bounds__(256) void k_prep_wo(
    const float* __restrict__ Wo, u16* __restrict__ wsu)
{
  const int bx = blockIdx.x;
  const int c0 = (bx >> 4) * 64, dd0 = (bx & 15) * 64;
  __shared__ float T[64][65];
  const int tid = threadIdx.x;
  for (int l = 0; l < 16; ++l) {
    int idx = tid + l * 256; int r = idx >> 6, c = idx & 63;
    T[r][c] = Wo[(size_t)(c0 + r) * 1024 + dd0 + c];
  }
  __syncthreads();
  u16* WOT = wsu + OFF_WOT;
  for (int l = 0; l < 16; ++l) {
    int idx = tid + l * 256; int r = idx >> 6, c = idx & 63;
    WOT[(size_t)(dd0 + r) * 1024 + c0 + c] = f2bf(T[c][r]);
  }
}

// ---------------------------------------------------------------------------
// Fused QKV projection: C[4096][3072] = Xh . (Wh+Wl), 2-term split.
// Grid 1536 = 32 row-tiles x 48 col-tiles (16 Q | 16 K | 16 V heads).
// Q: hi/lo stores; K: hi only; V: transposed single-bf16 VT[bh][k'][n].
// Computes bit-identical tiles to round-6's three projg<MODE> launches.
// ---------------------------------------------------------------------------
__global__ __launch_bounds__(256, 2) void k_projg(u16* __restrict__ wsu)
{
  const int bid = blockIdx.x;                // 1536
  const int s  = (bid & 7) * 192 + (bid >> 3);   // XCD-chunked (bijective)
  const int mt = s / 48, ct = s % 48;
  const int gm0 = mt * 128;
  const int j0 = ct * 64;                    // row in WALL
  const int qkv = ct >> 4, h = ct & 15;

  const u16* XH = wsu + OFF_XH;
  const u16* WH = wsu + OFF_WH;
  const u16* WL = wsu + OFF_WL;

  __shared__ __align__(16) u16 lds[16384];   // Ah[128][64] Bh[64][64] Bl
  u16* Ah = lds;
  u16* Bh = lds + 8192;
  u16* Bl = lds + 12288;

  const int tid = threadIdx.x;
  const int w = tid >> 6, l = tid & 63, lr = l & 15, lg = l >> 4;
  const int wm = w >> 1, wn = w & 1;

  const f32x4 fz = {0.f, 0.f, 0.f, 0.f};
  f32x4 acc[4][2];
  for (int i = 0; i < 4; ++i) for (int j = 0; j < 2; ++j) acc[i][j] = fz;

  for (int kt = 0; kt < 16; ++kt) {
    const int d0 = kt * 64;
    __syncthreads();
    #pragma unroll
    for (int it = 0; it < 8; ++it) {
      const int c = tid + it * 256;          // 0..2047 16B chunks
      const u16* src;
      if (c < 1024) {                        // A plane
        const int r = c >> 3, col8 = (c & 7) * 8;
        src = XH + (size_t)(gm0 + r) * 1024 + d0 + col8;
      } else {                               // B planes
        const int cc = c - 1024;
        const int plane = cc >> 9, c2 = cc & 511;
        const int r = c2 >> 3, col8 = (c2 & 7) * 8;
        src = (plane ? WL : WH) + (size_t)(j0 + r) * 1024 + d0 + col8;
      }
      gload16(src, lds + (size_t)c * 8);
    }
    __syncthreads();

    #pragma unroll
    for (int ks = 0; ks < 2; ++ks) {
      bf16x8 a_h[4], b_h[2], b_l[2];
      #pragma unroll
      for (int mf = 0; mf < 4; ++mf) {
        const int row = wm * 64 + mf * 16 + lr;
        a_h[mf] = frag(Ah + row * 64 + ks * 32 + lg * 8);
      }
      #pragma unroll
      for (int nf = 0; nf < 2; ++nf) {
        const int row = wn * 32 + nf * 16 + lr;
        b_h[nf] = frag(Bh + row * 64 + ks * 32 + lg * 8);
        b_l[nf] = frag(Bl + row * 64 + ks * 32 + lg * 8);
      }
      #pragma unroll
      for (int nf = 0; nf < 2; ++nf)
        #pragma unroll
        for (int mf = 0; mf < 4; ++mf) {
          acc[mf][nf] = mfma16(a_h[mf], b_h[nf], acc[mf][nf]);
          acc[mf][nf] = mfma16(a_h[mf], b_l[nf], acc[mf][nf]);
        }
    }
  }

  if (qkv == 0) {        // Q: hi/lo planes [bh][n][64]
    u16* Ph = wsu + OFF_QH;
    u16* Pl = wsu + OFF_QL;
    #pragma unroll
    for (int mf = 0; mf < 4; ++mf)
      #pragma unroll
      for (int nf = 0; nf < 2; ++nf)
        #pragma unroll
        for (int r = 0; r < 4; ++r) {
          const float v = acc[mf][nf][r];
          const int gn = gm0 + wm * 64 + mf * 16 + lg * 4 + r;
          const int b = gn >> 11, n = gn & 2047;
          const int kp = wn * 32 + nf * 16 + lr;
          const size_t o = ((size_t)(b * 16 + h) * 2048 + n) * 64 + kp;
          const u16 hi = f2bf(v);
          Ph[o] = hi;
          Pl[o] = f2bf(v - bf2f(hi));
        }
  } else if (qkv == 1) { // K: hi only
    u16* Ph = wsu + OFF_KH;
    #pragma unroll
    for (int mf = 0; mf < 4; ++mf)
      #pragma unroll
      for (int nf = 0; nf < 2; ++nf)
        #pragma unroll
        for (int r = 0; r < 4; ++r) {
          const int gn = gm0 + wm * 64 + mf * 16 + lg * 4 + r;
          const int b = gn >> 11, n = gn & 2047;
          const int kp = wn * 32 + nf * 16 + lr;
          Ph[((size_t)(b * 16 + h) * 2048 + n) * 64 + kp] = f2bf(acc[mf][nf][r]);
        }
  } else {               // V: transposed store VT[bh][k'][n]
    u16* VT = wsu + OFF_VT;
    #pragma unroll
    for (int mf = 0; mf < 4; ++mf)
      #pragma unroll
      for (int nf = 0; nf < 2; ++nf) {
        const int gn = gm0 + wm * 64 + mf * 16 + lg * 4;
        const int b = gn >> 11, n = gn & 2047;
        const int kp = wn * 32 + nf * 16 + lr;
        ushort4 p;
        p.x = f2bf(acc[mf][nf][0]); p.y = f2bf(acc[mf][nf][1]);
        p.z = f2bf(acc[mf][nf][2]); p.w = f2bf(acc[mf][nf][3]);
        *(ushort4*)&VT[((size_t)(b * 16 + h) * 64 + kp) * 2048 + n] = p;
      }
  }
}

// ---------------------------------------------------------------------------
// Pass 1 (i-split x4, 2-TERM: l_j = sum_i exp(Kh_j . (Qh+Ql)_i)), atomicAdd.
// [round-6 verbatim — matches pass2's S bitwise]
// ---------------------------------------------------------------------------
__global__ __launch_bounds__(256, 2) void k_pass1(
    u16* __restrict__ wsu, float* __restrict__ L)
{
  const int bid = blockIdx.x;                    // 2048
  const int swz = (bid & 7) * 256 + (bid >> 3);
  const int bh = swz >> 6;
  const int jtile = (swz >> 2) & 15;
  const int isl = swz & 3;
  const int j0 = jtile * 128;
  const u16* Qh = wsu + OFF_QH + (size_t)bh * 131072;
  const u16* Ql = wsu + OFF_QL + (size_t)bh * 131072;
  const u16* Kh = wsu + OFF_KH + (size_t)bh * 131072;

  __shared__ __align__(16) u16 lds[2][2][4096];   // [buf][Qhi,Qlo][64][64]

  const int tid = threadIdx.x;
  const int w = tid >> 6, l = tid & 63;
  const int il = l & 31, hi = l >> 5;

  bf16x8 kah[4];                                 // stationary K A-frags
  {
    const int jrow = j0 + w * 32 + il;
    #pragma unroll
    for (int ks = 0; ks < 4; ++ks)
      kah[ks] = frag(&Kh[(size_t)jrow * 64 + ks * 16 + hi * 8]);
  }

  auto stage = [&](int buf, int ic) {
    const int i0 = ic * 64;
    #pragma unroll
    for (int it = 0; it < 4; ++it) {
      const int c = tid + it * 256;              // 0..1023
      const int plane = c >> 9, cc = c & 511;
      const int r = cc >> 3, cl = cc & 7;
      const int sw8 = (cl ^ (r & 7)) * 8;        // inverse-swizzled source
      const u16* src = (plane ? Ql : Qh) + (size_t)(i0 + r) * 64 + sw8;
      gload16(src, &lds[buf][0][0] + (size_t)c * 8);
    }
  };

  const f32x16 fz16 = {0,0,0,0,0,0,0,0,0,0,0,0,0,0,0,0};
  float lsum[16] = {};
  const int icbase = isl * 8;

  stage(0, icbase);
  __syncthreads();
  int cur = 0;
  for (int ii = 0; ii < 8; ++ii) {
    if (ii < 7) stage(cur ^ 1, icbase + ii + 1);
    const u16* Qsh = &lds[cur][0][0];
    const u16* Qsl = &lds[cur][1][0];
    #pragma unroll
    for (int it2 = 0; it2 < 2; ++it2) {
      f32x16 s = fz16;
      const int qrow = it2 * 32 + il;
      #pragma unroll
      for (int ks = 0; ks < 4; ++ks) {
        const int ch = ((ks * 2 + hi) ^ (qrow & 7)) * 8;   // swizzled read
        s = mfma32(kah[ks], frag(&Qsh[qrow * 64 + ch]), s);
        s = mfma32(kah[ks], frag(&Qsl[qrow * 64 + ch]), s);
      }
      #pragma unroll
      for (int r = 0; r < 16; ++r) lsum[r] += __expf(s[r]);
    }
    __syncthreads();
    cur ^= 1;
  }

  #pragma unroll
  for (int r = 0; r < 16; ++r) {
    float v = lsum[r];
    v += __shfl_xor(v, 1);  v += __shfl_xor(v, 2);
    v += __shfl_xor(v, 4);  v += __shfl_xor(v, 8);
    v += __shfl_xor(v, 16);
    if (il == 0) {
      const int j = j0 + w * 32 + (r & 3) + 8 * (r >> 2) + 4 * hi;
      atomicAdd(&L[(size_t)bh * 2048 + j], v);
    }
  }
}

// ---------------------------------------------------------------------------
// Scale V^T by 1/l along n:  VT[bh][c][n] *= rcp(L[bh][n])   [round-6 verbatim]
// ---------------------------------------------------------------------------
__global__ __launch_bounds__(256) void k_scale_v(
    u16* __restrict__ wsu, const float* __restrict__ L)
{
  u16* VT = wsu + OFF_VT;
  const size_t vid = (size_t)blockIdx.x * 256 + threadIdx.x;  // 0..524287
  if (vid * 8 >= VT_ELEMS) return;
  const size_t base = vid * 8;
  const int n8 = (int)(vid & 255);
  const int bh = (int)(vid >> 14);
  ushort4 a = *(ushort4*)&VT[base];
  ushort4 b = *(ushort4*)&VT[base + 4];
  const float* Lp = L + (size_t)bh * 2048 + n8 * 8;
  a.x = f2bf(bf2f(a.x) * __builtin_amdgcn_rcpf(Lp[0]));
  a.y = f2bf(bf2f(a.y) * __builtin_amdgcn_rcpf(Lp[1]));
  a.z = f2bf(bf2f(a.z) * __builtin_amdgcn_rcpf(Lp[2]));
  a.w = f2bf(bf2f(a.w) * __builtin_amdgcn_rcpf(Lp[3]));
  b.x = f2bf(bf2f(b.x) * __builtin_amdgcn_rcpf(Lp[4]));
  b.y = f2bf(bf2f(b.y) * __builtin_amdgcn_rcpf(Lp[5]));
  b.z = f2bf(bf2f(b.z) * __builtin_amdgcn_rcpf(Lp[6]));
  b.w = f2bf(bf2f(b.w) * __builtin_amdgcn_rcpf(Lp[7]));
  *(ushort4*)&VT[base] = a;
  *(ushort4*)&VT[base + 4] = b;
}

// ---------------------------------------------------------------------------
// Pass 2 (4-wave, 2-TERM S, in-register P): AV[i][c] = sum_j exp(S_ij) V'[j][c]
// [round-6 verbatim]
// ---------------------------------------------------------------------------
__global__ __launch_bounds__(256, 2) void k_pass2(u16* __restrict__ wsu)
{
  const int bid = blockIdx.x;                  // 512
  const int swz = (bid & 7) * 64 + (bid >> 3);
  const int itile = swz & 15, bh = swz >> 4;
  const int i0 = itile * 128;
  const u16* Qh = wsu + OFF_QH + (size_t)bh * 131072;
  const u16* Ql = wsu + OFF_QL + (size_t)bh * 131072;
  const u16* Kh = wsu + OFF_KH + (size_t)bh * 131072;
  const u16* VT = wsu + OFF_VT + (size_t)bh * 131072;

  __shared__ __align__(16) u16 lds[2][2][4096];  // [buf][Kh,V][64][64]

  const int tid = threadIdx.x;
  const int w = tid >> 6, l = tid & 63;
  const int il = l & 31, hi = l >> 5;

  bf16x8 qbh[4], qbl[4];                       // stationary Q B-frags
  {
    const int irow = i0 + w * 32 + il;
    #pragma unroll
    for (int ks = 0; ks < 4; ++ks) {
      const size_t o = (size_t)irow * 64 + ks * 16 + hi * 8;
      qbh[ks] = frag(&Qh[o]);
      qbl[ks] = frag(&Ql[o]);
    }
  }

  auto stage = [&](int buf, int jc) {
    const int j0 = jc * 64;
    #pragma unroll
    for (int it = 0; it < 4; ++it) {
      const int c = tid + it * 256;            // 0..1023
      const int plane = c >> 9, cc = c & 511;
      const int r = cc >> 3, cl = cc & 7;
      const int sw8 = (cl ^ (r & 7)) * 8;
      const u16* src = plane == 0 ? Kh + (size_t)(j0 + r) * 64 + sw8
                                  : VT + (size_t)r * 2048 + j0 + sw8;
      gload16(src, &lds[buf][0][0] + (size_t)c * 8);
    }
  };

  const f32x16 fz16 = {0,0,0,0,0,0,0,0,0,0,0,0,0,0,0,0};
  f32x16 acc[2]; acc[0] = fz16; acc[1] = fz16;

  stage(0, 0);
  __syncthreads();
  int cur = 0;
  for (int jc = 0; jc < 32; ++jc) {
    if (jc < 31) stage(cur ^ 1, jc + 1);
    const u16* Ksh = &lds[cur][0][0];
    const u16* Vs  = &lds[cur][1][0];
    #pragma unroll
    for (int jt = 0; jt < 2; ++jt) {
      f32x16 s = fz16;
      const int jrow = jt * 32 + il;
      #pragma unroll
      for (int ks = 0; ks < 4; ++ks) {
        const int ch = ((ks * 2 + hi) ^ (jrow & 7)) * 8;
        bf16x8 ka = frag(&Ksh[jrow * 64 + ch]);
        s = mfma32(ka, qbh[ks], s);
        s = mfma32(ka, qbl[ks], s);
      }
      float p[16];
      #pragma unroll
      for (int r = 0; r < 16; ++r) p[r] = __expf(s[r]);
      u32 a0 = cvtpk(p[0],  p[1]),  b0 = cvtpk(p[4],  p[5]);
      u32 a1 = cvtpk(p[2],  p[3]),  b1 = cvtpk(p[6],  p[7]);
      u32 a2 = cvtpk(p[8],  p[9]),  b2 = cvtpk(p[12], p[13]);
      u32 a3 = cvtpk(p[10], p[11]), b3 = cvtpk(p[14], p[15]);
      pswap(a0, b0); pswap(a1, b1); pswap(a2, b2); pswap(a3, b3);
      u32x4 pw0 = {a0, a1, b0, b1};            // k = j 0..15 of this jt
      u32x4 pw1 = {a2, a3, b2, b3};            // k = j 16..31
      bf16x8 pa0 = __builtin_bit_cast(bf16x8, pw0);
      bf16x8 pa1 = __builtin_bit_cast(bf16x8, pw1);
      #pragma unroll
      for (int cb = 0; cb < 2; ++cb) {
        const int crow = cb * 32 + il;
        const int c0 = ((jt * 4 + 0 + hi) ^ (crow & 7)) * 8;
        const int c1 = ((jt * 4 + 2 + hi) ^ (crow & 7)) * 8;
        bf16x8 vb0 = frag(&Vs[crow * 64 + c0]);
        bf16x8 vb1 = frag(&Vs[crow * 64 + c1]);
        acc[cb] = mfma32(pa0, vb0, acc[cb]);
        acc[cb] = mfma32(pa1, vb1, acc[cb]);
      }
    }
    __syncthreads();
    cur ^= 1;
  }

  u16* AVh = wsu + OFF_AVH;                    // hi only (1-term outproj)
  #pragma unroll
  for (int cb = 0; cb < 2; ++cb)
    #pragma unroll
    for (int r = 0; r < 16; ++r) {
      const int iloc = (r & 3) + 8 * (r >> 2) + 4 * hi;
      const int g = i0 + w * 32 + iloc;
      const int c = cb * 32 + il;
      AVh[((size_t)bh * 2048 + g) * 64 + c] = f2bf(acc[cb][r]);
    }
}

// ---------------------------------------------------------------------------
// Output projection: Out = AVh[4096][1024] . WO   (1-term)  [round-6 verbatim]
// ---------------------------------------------------------------------------
__global__ __launch_bounds__(256, 2) void k_outproj(
    const u16* __restrict__ wsu, float* __restrict__ Out)
{
  const int bx = blockIdx.x;                 // 256 = gm(32) * dn(8)
  const int gm = bx >> 3, dn = bx & 7;
  const int g0 = gm * 128, d0 = dn * 128;
  const u16* AVh = wsu + OFF_AVH;
  const u16* WOT = wsu + OFF_WOT;

  __shared__ __align__(16) u16 Ah[128][72], Bs[128][72];

  const int tid = threadIdx.x;
  const int w = tid >> 6, l = tid & 63, lr = l & 15, lg = l >> 4;
  const int wm = w >> 1, wn = w & 1;

  const f32x4 fz = {0.f, 0.f, 0.f, 0.f};
  f32x4 acc[4][4];
  for (int i = 0; i < 4; ++i) for (int j = 0; j < 4; ++j) acc[i][j] = fz;

  for (int kt = 0; kt < 16; ++kt) {
    const int c0 = kt * 64;
    __syncthreads();
    for (int s = 0; s < 8; ++s) {            // 2 planes x 1024 uint4
      int idx = tid + s * 256;
      int sel = idx >> 10, i2 = idx & 1023;
      int r = i2 >> 3, c8 = (i2 & 7) * 8;
      const u16* src = sel == 0 ? AVh + (size_t)(g0 + r) * 1024 + c0 + c8
                                : WOT + (size_t)(d0 + r) * 1024 + c0 + c8;
      u16* dst = sel == 0 ? &Ah[r][c8] : &Bs[r][c8];
      *(uint4*)dst = *(const uint4*)src;
    }
    __syncthreads();
    #pragma unroll
    for (int ks = 0; ks < 2; ++ks) {
      bf16x8 ah[4];
      #pragma unroll
      for (int mf = 0; mf < 4; ++mf)
        ah[mf] = frag(&Ah[wm * 64 + mf * 16 + lr][ks * 32 + lg * 8]);
      #pragma unroll
      for (int nf = 0; nf < 4; ++nf) {
        bf16x8 bfv = frag(&Bs[wn * 64 + nf * 16 + lr][ks * 32 + lg * 8]);
        #pragma unroll
        for (int mf = 0; mf < 4; ++mf)
          acc[mf][nf] = mfma16(ah[mf], bfv, acc[mf][nf]);
      }
    }
  }
  #pragma unroll
  for (int mf = 0; mf < 4; ++mf)
    #pragma unroll
    for (int nf = 0; nf < 4; ++nf)
      #pragma unroll
      for (int r = 0; r < 4; ++r) {
        const int g = g0 + wm * 64 + mf * 16 + lg * 4 + r;
        const int d = d0 + wn * 64 + nf * 16 + lr;
        Out[(size_t)g * 1024 + d] = acc[mf][nf][r];
      }
}

} // anonymous namespace

extern "C" void kernel_launch(void* const* d_in, const int* in_sizes, int n_in,
                              void* d_out, int out_size, void* d_ws, size_t ws_size,
                              hipStream_t stream) {
  const float* X  = (const float*)d_in[0];
  const float* Wq = (const float*)d_in[1];
  const float* Wk = (const float*)d_in[2];
  const float* Wv = (const float*)d_in[3];
  const float* Wo = (const float*)d_in[4];
  float* out = (float*)d_out;
  u16* wsu = (u16*)d_ws;
  float* L = (float*)(wsu + OFF_L);

  k_prep_x    <<<4096, 256, 0, stream>>>(X, wsu);
  k_zero_l    <<<64,   256, 0, stream>>>(L);
  k_prep_wall <<<768,  256, 0, stream>>>(Wq, Wk, Wv, wsu);
  k_prep_wo   <<<256,  256, 0, stream>>>(Wo, wsu);
  k_projg     <<<1536, 256, 0, stream>>>(wsu);
  k_pass1     <<<2048, 256, 0, stream>>>(wsu, L);
  k_scale_v   <<<2048, 256, 0, stream>>>(wsu, L);
  k_pass2     <<<512,  256, 0, stream>>>(wsu);
  k_outproj   <<<256,  256, 0, stream>>>(wsu, out);
}

// Round 10
// 210.675 us; speedup vs baseline: 1.4177x; 1.1591x over previous
//
#include <hip/hip_runtime.h>
#include <math.h>

namespace {

typedef unsigned short u16;
typedef unsigned int   u32;
typedef __bf16 bf16x8 __attribute__((ext_vector_type(8)));
typedef float  f32x4  __attribute__((ext_vector_type(4)));
typedef float  f32x16 __attribute__((ext_vector_type(16)));
typedef u32    u32x4  __attribute__((ext_vector_type(4)));

// ---- workspace layout (u16 element offsets) --------------------------------
constexpr size_t OFF_XH  = 0;          // [4096][1024] bf16 hi of X (dead after proj)
constexpr size_t OFF_WH  = 4194304;    // [3072 j=qkv*1024+h*64+k'][1024 d] hi
constexpr size_t OFF_WL  = 7340032;    //                                   lo
constexpr size_t OFF_QH  = 10485760;   // [32 bh][2048][64]
constexpr size_t OFF_QL  = 14680064;   // [32 bh][2048][64]
constexpr size_t OFF_KH  = 18874368;   // [32 bh][2048][64]
constexpr size_t OFF_VT  = 23068672;   // [32 bh][64][2048]
constexpr size_t OFF_WOT = 27262976;   // [1024 d'][1024 c]
constexpr size_t OFF_L   = 28311552;   // f32[65536] raw column sums (131072 u16)
constexpr size_t OFF_AVH = 0;          // aliases XH (dead after proj)
// end = 28,442,624 u16 = 56.9 MB  (< 65.3 MB proven safe)

constexpr size_t VT_ELEMS = (size_t)32 * 64 * 2048;       // 4,194,304

__device__ __forceinline__ u16 f2bf(float x) {            // RNE fp32 -> bf16
  union { float f; unsigned u; } v; v.f = x;
  unsigned r = v.u + 0x7FFFu + ((v.u >> 16) & 1u);
  return (u16)(r >> 16);
}
__device__ __forceinline__ float bf2f(u16 b) {
  union { unsigned u; float f; } v; v.u = (unsigned)b << 16; return v.f;
}
__device__ __forceinline__ bf16x8 frag(const u16* p) {
  return *reinterpret_cast<const bf16x8*>(p);
}
__device__ __forceinline__ f32x4 mfma16(bf16x8 a, bf16x8 b, f32x4 c) {
  return __builtin_amdgcn_mfma_f32_16x16x32_bf16(a, b, c, 0, 0, 0);
}
__device__ __forceinline__ f32x16 mfma32(bf16x8 a, bf16x8 b, f32x16 c) {
  return __builtin_amdgcn_mfma_f32_32x32x16_bf16(a, b, c, 0, 0, 0);
}
__device__ __forceinline__ void gload16(const void* g, void* l) {
  __builtin_amdgcn_global_load_lds(
      (const __attribute__((address_space(1))) u32*)g,
      (__attribute__((address_space(3))) u32*)l, 16, 0, 0);
}
__device__ __forceinline__ u32 cvtpk(float lo, float hi) {
  u32 r;
  asm("v_cvt_pk_bf16_f32 %0, %1, %2" : "=v"(r) : "v"(lo), "v"(hi));
  return r;
}
__device__ __forceinline__ void pswap(u32& a, u32& b) {
  asm("v_permlane32_swap_b32 %0, %1" : "+v"(a), "+v"(b));
}

// ---------------------------------------------------------------------------
// Prep X: X f32 -> Xh bf16 (hi only); blocks <64 also zero the L accumulator.
// ---------------------------------------------------------------------------
__global__ __launch_bounds__(256) void k_prep_x(
    const float* __restrict__ X, u16* __restrict__ wsu)
{
  u16* Xh = wsu + OFF_XH;
  const size_t i = ((size_t)blockIdx.x * 256 + threadIdx.x) * 4;  // 4096 blocks
  const float4 v = *(const float4*)&X[i];
  ushort4 hh;
  hh.x = f2bf(v.x); hh.y = f2bf(v.y); hh.z = f2bf(v.z); hh.w = f2bf(v.w);
  *(ushort4*)&Xh[i] = hh;
  if (blockIdx.x < 64) {                       // zero L: 64*256*4 = 65536 f32
    float* L = (float*)(wsu + OFF_L);
    const size_t li = ((size_t)blockIdx.x * 256 + threadIdx.x) * 4;
    *(float4*)&L[li] = make_float4(0.f, 0.f, 0.f, 0.f);
  }
}

// ---------------------------------------------------------------------------
// Prep weights: bx<768 -> transpose+hi/lo split W_{q,k,v} into WALL[j][d];
// bx>=768 -> transpose W_O into WOT[d'][c].
// ---------------------------------------------------------------------------
__global__ __launch_bounds__(256) void k_prep_w(
    const float* __restrict__ Wq, const float* __restrict__ Wk,
    const float* __restrict__ Wv, const float* __restrict__ Wo,
    u16* __restrict__ wsu)
{
  const int bx = blockIdx.x;                 // 1024
  const int tid = threadIdx.x;
  __shared__ float T[64][65];
  if (bx < 768) {                            // 768 = qkv(3)*h(16)*dchunk(16)
    const int qkv = bx >> 8, h = (bx >> 4) & 15, dc = bx & 15;
    const float* W = qkv == 0 ? Wq : qkv == 1 ? Wk : Wv;
    const int d0 = dc * 64;
    for (int l = 0; l < 16; ++l) {
      int idx = tid + l * 256; int r = idx >> 6, c = idx & 63;  // r=d, c=k'
      T[r][c] = W[((size_t)h * 1024 + d0 + r) * 64 + c];
    }
    __syncthreads();
    u16* Wh = wsu + OFF_WH;
    u16* Wl = wsu + OFF_WL;
    for (int l = 0; l < 16; ++l) {
      int idx = tid + l * 256; int r = idx >> 6, c = idx & 63;  // r=k', c=d
      float v = T[c][r];
      u16 hi = f2bf(v);
      size_t o = (size_t)((qkv * 16 + h) * 64 + r) * 1024 + d0 + c;
      Wh[o] = hi;
      Wl[o] = f2bf(v - bf2f(hi));
    }
  } else {                                   // 256 = cchunk(16)*dchunk(16)
    const int b2 = bx - 768;
    const int c0 = (b2 >> 4) * 64, dd0 = (b2 & 15) * 64;
    for (int l = 0; l < 16; ++l) {
      int idx = tid + l * 256; int r = idx >> 6, c = idx & 63;
      T[r][c] = Wo[(size_t)(c0 + r) * 1024 + dd0 + c];
    }
    __syncthreads();
    u16* WOT = wsu + OFF_WOT;
    for (int l = 0; l < 16; ++l) {
      int idx = tid + l * 256; int r = idx >> 6, c = idx & 63;
      WOT[(size_t)(dd0 + r) * 1024 + c0 + c] = f2bf(T[c][r]);
    }
  }
}

// ---------------------------------------------------------------------------
// Fused QKV projection: C[4096][3072] = Xh . (Wh+Wl), 2-term split.
// Column-ownership XCD swizzle: each XCD owns 6 col-tiles (B strip 1.5 MB,
// L2-resident); the 6 same-row blocks are dispatch-adjacent (A strip L2-hits).
// ---------------------------------------------------------------------------
__global__ __launch_bounds__(256, 2) void k_projg(u16* __restrict__ wsu)
{
  const int bid = blockIdx.x;                // 1536
  const int xcd = bid & 7, local = bid >> 3; // local 0..191
  const int ct = xcd * 6 + (local % 6);      // 48 col-tiles, 6 per XCD
  const int mt = local / 6;                  // 32 row-tiles
  const int gm0 = mt * 128;
  const int j0 = ct * 64;                    // row in WALL
  const int qkv = ct >> 4, h = ct & 15;

  const u16* XH = wsu + OFF_XH;
  const u16* WH = wsu + OFF_WH;
  const u16* WL = wsu + OFF_WL;

  __shared__ __align__(16) u16 lds[16384];   // Ah[128][64] Bh[64][64] Bl
  u16* Ah = lds;
  u16* Bh = lds + 8192;
  u16* Bl = lds + 12288;

  const int tid = threadIdx.x;
  const int w = tid >> 6, l = tid & 63, lr = l & 15, lg = l >> 4;
  const int wm = w >> 1, wn = w & 1;

  const f32x4 fz = {0.f, 0.f, 0.f, 0.f};
  f32x4 acc[4][2];
  for (int i = 0; i < 4; ++i) for (int j = 0; j < 2; ++j) acc[i][j] = fz;

  for (int kt = 0; kt < 16; ++kt) {
    const int d0 = kt * 64;
    __syncthreads();
    #pragma unroll
    for (int it = 0; it < 8; ++it) {
      const int c = tid + it * 256;          // 0..2047 16B chunks
      const u16* src;
      if (c < 1024) {                        // A plane
        const int r = c >> 3, col8 = (c & 7) * 8;
        src = XH + (size_t)(gm0 + r) * 1024 + d0 + col8;
      } else {                               // B planes
        const int cc = c - 1024;
        const int plane = cc >> 9, c2 = cc & 511;
        const int r = c2 >> 3, col8 = (c2 & 7) * 8;
        src = (plane ? WL : WH) + (size_t)(j0 + r) * 1024 + d0 + col8;
      }
      gload16(src, lds + (size_t)c * 8);
    }
    __syncthreads();

    #pragma unroll
    for (int ks = 0; ks < 2; ++ks) {
      bf16x8 a_h[4], b_h[2], b_l[2];
      #pragma unroll
      for (int mf = 0; mf < 4; ++mf) {
        const int row = wm * 64 + mf * 16 + lr;
        a_h[mf] = frag(Ah + row * 64 + ks * 32 + lg * 8);
      }
      #pragma unroll
      for (int nf = 0; nf < 2; ++nf) {
        const int row = wn * 32 + nf * 16 + lr;
        b_h[nf] = frag(Bh + row * 64 + ks * 32 + lg * 8);
        b_l[nf] = frag(Bl + row * 64 + ks * 32 + lg * 8);
      }
      #pragma unroll
      for (int nf = 0; nf < 2; ++nf)
        #pragma unroll
        for (int mf = 0; mf < 4; ++mf) {
          acc[mf][nf] = mfma16(a_h[mf], b_h[nf], acc[mf][nf]);
          acc[mf][nf] = mfma16(a_h[mf], b_l[nf], acc[mf][nf]);
        }
    }
  }

  if (qkv == 0) {        // Q: hi/lo planes [bh][n][64]
    u16* Ph = wsu + OFF_QH;
    u16* Pl = wsu + OFF_QL;
    #pragma unroll
    for (int mf = 0; mf < 4; ++mf)
      #pragma unroll
      for (int nf = 0; nf < 2; ++nf)
        #pragma unroll
        for (int r = 0; r < 4; ++r) {
          const float v = acc[mf][nf][r];
          const int gn = gm0 + wm * 64 + mf * 16 + lg * 4 + r;
          const int b = gn >> 11, n = gn & 2047;
          const int kp = wn * 32 + nf * 16 + lr;
          const size_t o = ((size_t)(b * 16 + h) * 2048 + n) * 64 + kp;
          const u16 hi = f2bf(v);
          Ph[o] = hi;
          Pl[o] = f2bf(v - bf2f(hi));
        }
  } else if (qkv == 1) { // K: hi only
    u16* Ph = wsu + OFF_KH;
    #pragma unroll
    for (int mf = 0; mf < 4; ++mf)
      #pragma unroll
      for (int nf = 0; nf < 2; ++nf)
        #pragma unroll
        for (int r = 0; r < 4; ++r) {
          const int gn = gm0 + wm * 64 + mf * 16 + lg * 4 + r;
          const int b = gn >> 11, n = gn & 2047;
          const int kp = wn * 32 + nf * 16 + lr;
          Ph[((size_t)(b * 16 + h) * 2048 + n) * 64 + kp] = f2bf(acc[mf][nf][r]);
        }
  } else {               // V: transposed store VT[bh][k'][n]
    u16* VT = wsu + OFF_VT;
    #pragma unroll
    for (int mf = 0; mf < 4; ++mf)
      #pragma unroll
      for (int nf = 0; nf < 2; ++nf) {
        const int gn = gm0 + wm * 64 + mf * 16 + lg * 4;
        const int b = gn >> 11, n = gn & 2047;
        const int kp = wn * 32 + nf * 16 + lr;
        ushort4 p;
        p.x = f2bf(acc[mf][nf][0]); p.y = f2bf(acc[mf][nf][1]);
        p.z = f2bf(acc[mf][nf][2]); p.w = f2bf(acc[mf][nf][3]);
        *(ushort4*)&VT[((size_t)(b * 16 + h) * 64 + kp) * 2048 + n] = p;
      }
  }
}

// ---------------------------------------------------------------------------
// Pass 1 (i-split x4, 2-TERM: l_j = sum_i exp(Kh_j . (Qh+Ql)_i)), atomicAdd.
// [round-9 verbatim]
// ---------------------------------------------------------------------------
__global__ __launch_bounds__(256, 2) void k_pass1(
    u16* __restrict__ wsu, float* __restrict__ L)
{
  const int bid = blockIdx.x;                    // 2048
  const int swz = (bid & 7) * 256 + (bid >> 3);
  const int bh = swz >> 6;
  const int jtile = (swz >> 2) & 15;
  const int isl = swz & 3;
  const int j0 = jtile * 128;
  const u16* Qh = wsu + OFF_QH + (size_t)bh * 131072;
  const u16* Ql = wsu + OFF_QL + (size_t)bh * 131072;
  const u16* Kh = wsu + OFF_KH + (size_t)bh * 131072;

  __shared__ __align__(16) u16 lds[2][2][4096];   // [buf][Qhi,Qlo][64][64]

  const int tid = threadIdx.x;
  const int w = tid >> 6, l = tid & 63;
  const int il = l & 31, hi = l >> 5;

  bf16x8 kah[4];                                 // stationary K A-frags
  {
    const int jrow = j0 + w * 32 + il;
    #pragma unroll
    for (int ks = 0; ks < 4; ++ks)
      kah[ks] = frag(&Kh[(size_t)jrow * 64 + ks * 16 + hi * 8]);
  }

  auto stage = [&](int buf, int ic) {
    const int i0 = ic * 64;
    #pragma unroll
    for (int it = 0; it < 4; ++it) {
      const int c = tid + it * 256;              // 0..1023
      const int plane = c >> 9, cc = c & 511;
      const int r = cc >> 3, cl = cc & 7;
      const int sw8 = (cl ^ (r & 7)) * 8;        // inverse-swizzled source
      const u16* src = (plane ? Ql : Qh) + (size_t)(i0 + r) * 64 + sw8;
      gload16(src, &lds[buf][0][0] + (size_t)c * 8);
    }
  };

  const f32x16 fz16 = {0,0,0,0,0,0,0,0,0,0,0,0,0,0,0,0};
  float lsum[16] = {};
  const int icbase = isl * 8;

  stage(0, icbase);
  __syncthreads();
  int cur = 0;
  for (int ii = 0; ii < 8; ++ii) {
    if (ii < 7) stage(cur ^ 1, icbase + ii + 1);
    const u16* Qsh = &lds[cur][0][0];
    const u16* Qsl = &lds[cur][1][0];
    #pragma unroll
    for (int it2 = 0; it2 < 2; ++it2) {
      f32x16 s = fz16;
      const int qrow = it2 * 32 + il;
      #pragma unroll
      for (int ks = 0; ks < 4; ++ks) {
        const int ch = ((ks * 2 + hi) ^ (qrow & 7)) * 8;   // swizzled read
        s = mfma32(kah[ks], frag(&Qsh[qrow * 64 + ch]), s);
        s = mfma32(kah[ks], frag(&Qsl[qrow * 64 + ch]), s);
      }
      #pragma unroll
      for (int r = 0; r < 16; ++r) lsum[r] += __expf(s[r]);
    }
    __syncthreads();
    cur ^= 1;
  }

  #pragma unroll
  for (int r = 0; r < 16; ++r) {
    float v = lsum[r];
    v += __shfl_xor(v, 1);  v += __shfl_xor(v, 2);
    v += __shfl_xor(v, 4);  v += __shfl_xor(v, 8);
    v += __shfl_xor(v, 16);
    if (il == 0) {
      const int j = j0 + w * 32 + (r & 3) + 8 * (r >> 2) + 4 * hi;
      atomicAdd(&L[(size_t)bh * 2048 + j], v);
    }
  }
}

// ---------------------------------------------------------------------------
// Scale V^T by 1/l along n:  VT[bh][c][n] *= rcp(L[bh][n])   [round-9 verbatim]
// ---------------------------------------------------------------------------
__global__ __launch_bounds__(256) void k_scale_v(
    u16* __restrict__ wsu, const float* __restrict__ L)
{
  u16* VT = wsu + OFF_VT;
  const size_t vid = (size_t)blockIdx.x * 256 + threadIdx.x;  // 0..524287
  if (vid * 8 >= VT_ELEMS) return;
  const size_t base = vid * 8;
  const int n8 = (int)(vid & 255);
  const int bh = (int)(vid >> 14);
  ushort4 a = *(ushort4*)&VT[base];
  ushort4 b = *(ushort4*)&VT[base + 4];
  const float* Lp = L + (size_t)bh * 2048 + n8 * 8;
  a.x = f2bf(bf2f(a.x) * __builtin_amdgcn_rcpf(Lp[0]));
  a.y = f2bf(bf2f(a.y) * __builtin_amdgcn_rcpf(Lp[1]));
  a.z = f2bf(bf2f(a.z) * __builtin_amdgcn_rcpf(Lp[2]));
  a.w = f2bf(bf2f(a.w) * __builtin_amdgcn_rcpf(Lp[3]));
  b.x = f2bf(bf2f(b.x) * __builtin_amdgcn_rcpf(Lp[4]));
  b.y = f2bf(bf2f(b.y) * __builtin_amdgcn_rcpf(Lp[5]));
  b.z = f2bf(bf2f(b.z) * __builtin_amdgcn_rcpf(Lp[6]));
  b.w = f2bf(bf2f(b.w) * __builtin_amdgcn_rcpf(Lp[7]));
  *(ushort4*)&VT[base] = a;
  *(ushort4*)&VT[base + 4] = b;
}

// ---------------------------------------------------------------------------
// Pass 2 (4-wave, 2-TERM S, in-register P): AV[i][c] = sum_j exp(S_ij) V'[j][c]
// [round-9 verbatim]
// ---------------------------------------------------------------------------
__global__ __launch_bounds__(256, 2) void k_pass2(u16* __restrict__ wsu)
{
  const int bid = blockIdx.x;                  // 512
  const int swz = (bid & 7) * 64 + (bid >> 3);
  const int itile = swz & 15, bh = swz >> 4;
  const int i0 = itile * 128;
  const u16* Qh = wsu + OFF_QH + (size_t)bh * 131072;
  const u16* Ql = wsu + OFF_QL + (size_t)bh * 131072;
  const u16* Kh = wsu + OFF_KH + (size_t)bh * 131072;
  const u16* VT = wsu + OFF_VT + (size_t)bh * 131072;

  __shared__ __align__(16) u16 lds[2][2][4096];  // [buf][Kh,V][64][64]

  const int tid = threadIdx.x;
  const int w = tid >> 6, l = tid & 63;
  const int il = l & 31, hi = l >> 5;

  bf16x8 qbh[4], qbl[4];                       // stationary Q B-frags
  {
    const int irow = i0 + w * 32 + il;
    #pragma unroll
    for (int ks = 0; ks < 4; ++ks) {
      const size_t o = (size_t)irow * 64 + ks * 16 + hi * 8;
      qbh[ks] = frag(&Qh[o]);
      qbl[ks] = frag(&Ql[o]);
    }
  }

  auto stage = [&](int buf, int jc) {
    const int j0 = jc * 64;
    #pragma unroll
    for (int it = 0; it < 4; ++it) {
      const int c = tid + it * 256;            // 0..1023
      const int plane = c >> 9, cc = c & 511;
      const int r = cc >> 3, cl = cc & 7;
      const int sw8 = (cl ^ (r & 7)) * 8;
      const u16* src = plane == 0 ? Kh + (size_t)(j0 + r) * 64 + sw8
                                  : VT + (size_t)r * 2048 + j0 + sw8;
      gload16(src, &lds[buf][0][0] + (size_t)c * 8);
    }
  };

  const f32x16 fz16 = {0,0,0,0,0,0,0,0,0,0,0,0,0,0,0,0};
  f32x16 acc[2]; acc[0] = fz16; acc[1] = fz16;

  stage(0, 0);
  __syncthreads();
  int cur = 0;
  for (int jc = 0; jc < 32; ++jc) {
    if (jc < 31) stage(cur ^ 1, jc + 1);
    const u16* Ksh = &lds[cur][0][0];
    const u16* Vs  = &lds[cur][1][0];
    #pragma unroll
    for (int jt = 0; jt < 2; ++jt) {
      f32x16 s = fz16;
      const int jrow = jt * 32 + il;
      #pragma unroll
      for (int ks = 0; ks < 4; ++ks) {
        const int ch = ((ks * 2 + hi) ^ (jrow & 7)) * 8;
        bf16x8 ka = frag(&Ksh[jrow * 64 + ch]);
        s = mfma32(ka, qbh[ks], s);
        s = mfma32(ka, qbl[ks], s);
      }
      float p[16];
      #pragma unroll
      for (int r = 0; r < 16; ++r) p[r] = __expf(s[r]);
      u32 a0 = cvtpk(p[0],  p[1]),  b0 = cvtpk(p[4],  p[5]);
      u32 a1 = cvtpk(p[2],  p[3]),  b1 = cvtpk(p[6],  p[7]);
      u32 a2 = cvtpk(p[8],  p[9]),  b2 = cvtpk(p[12], p[13]);
      u32 a3 = cvtpk(p[10], p[11]), b3 = cvtpk(p[14], p[15]);
      pswap(a0, b0); pswap(a1, b1); pswap(a2, b2); pswap(a3, b3);
      u32x4 pw0 = {a0, a1, b0, b1};            // k = j 0..15 of this jt
      u32x4 pw1 = {a2, a3, b2, b3};            // k = j 16..31
      bf16x8 pa0 = __builtin_bit_cast(bf16x8, pw0);
      bf16x8 pa1 = __builtin_bit_cast(bf16x8, pw1);
      #pragma unroll
      for (int cb = 0; cb < 2; ++cb) {
        const int crow = cb * 32 + il;
        const int c0 = ((jt * 4 + 0 + hi) ^ (crow & 7)) * 8;
        const int c1 = ((jt * 4 + 2 + hi) ^ (crow & 7)) * 8;
        bf16x8 vb0 = frag(&Vs[crow * 64 + c0]);
        bf16x8 vb1 = frag(&Vs[crow * 64 + c1]);
        acc[cb] = mfma32(pa0, vb0, acc[cb]);
        acc[cb] = mfma32(pa1, vb1, acc[cb]);
      }
    }
    __syncthreads();
    cur ^= 1;
  }

  u16* AVh = wsu + OFF_AVH;                    // hi only (1-term outproj)
  #pragma unroll
  for (int cb = 0; cb < 2; ++cb)
    #pragma unroll
    for (int r = 0; r < 16; ++r) {
      const int iloc = (r & 3) + 8 * (r >> 2) + 4 * hi;
      const int g = i0 + w * 32 + iloc;
      const int c = cb * 32 + il;
      AVh[((size_t)bh * 2048 + g) * 64 + c] = f2bf(acc[cb][r]);
    }
}

// ---------------------------------------------------------------------------
// Output projection: Out = AVh[4096][1024] . WO  (1-term)
// Same math/order as round-9 (bitwise-identical output); staging switched
// from uint4 VGPR round-trips to global_load_lds w16 into linear LDS.
// ---------------------------------------------------------------------------
__global__ __launch_bounds__(256, 2) void k_outproj(
    const u16* __restrict__ wsu, float* __restrict__ Out)
{
  const int bx = blockIdx.x;                 // 256 = gm(32) * dn(8)
  const int gm = bx >> 3, dn = bx & 7;       // dn == bid&7: per-XCD WOT strip
  const int g0 = gm * 128, d0 = dn * 128;
  const u16* AVh = wsu + OFF_AVH;
  const u16* WOT = wsu + OFF_WOT;

  __shared__ __align__(16) u16 lds[16384];   // A[128][64] | B[128][64]
  u16* As = lds;
  u16* Bs = lds + 8192;

  const int tid = threadIdx.x;
  const int w = tid >> 6, l = tid & 63, lr = l & 15, lg = l >> 4;
  const int wm = w >> 1, wn = w & 1;

  const f32x4 fz = {0.f, 0.f, 0.f, 0.f};
  f32x4 acc[4][4];
  for (int i = 0; i < 4; ++i) for (int j = 0; j < 4; ++j) acc[i][j] = fz;

  for (int kt = 0; kt < 16; ++kt) {
    const int c0 = kt * 64;
    __syncthreads();
    #pragma unroll
    for (int it = 0; it < 8; ++it) {
      const int c = tid + it * 256;          // 0..2047 16B chunks
      const u16* src;
      if (c < 1024) {                        // A: AVh rows g0..g0+127
        const int r = c >> 3, col8 = (c & 7) * 8;
        src = AVh + (size_t)(g0 + r) * 1024 + c0 + col8;
      } else {                               // B: WOT rows d0..d0+127
        const int cc = c - 1024;
        const int r = cc >> 3, col8 = (cc & 7) * 8;
        src = WOT + (size_t)(d0 + r) * 1024 + c0 + col8;
      }
      gload16(src, lds + (size_t)c * 8);
    }
    __syncthreads();
    #pragma unroll
    for (int ks = 0; ks < 2; ++ks) {
      bf16x8 ah[4];
      #pragma unroll
      for (int mf = 0; mf < 4; ++mf)
        ah[mf] = frag(As + (wm * 64 + mf * 16 + lr) * 64 + ks * 32 + lg * 8);
      #pragma unroll
      for (int nf = 0; nf < 4; ++nf) {
        bf16x8 bfv = frag(Bs + (wn * 64 + nf * 16 + lr) * 64 + ks * 32 + lg * 8);
        #pragma unroll
        for (int mf = 0; mf < 4; ++mf)
          acc[mf][nf] = mfma16(ah[mf], bfv, acc[mf][nf]);
      }
    }
  }
  #pragma unroll
  for (int mf = 0; mf < 4; ++mf)
    #pragma unroll
    for (int nf = 0; nf < 4; ++nf)
      #pragma unroll
      for (int r = 0; r < 4; ++r) {
        const int g = g0 + wm * 64 + mf * 16 + lg * 4 + r;
        const int d = d0 + wn * 64 + nf * 16 + lr;
        Out[(size_t)g * 1024 + d] = acc[mf][nf][r];
      }
}

} // anonymous namespace

extern "C" void kernel_launch(void* const* d_in, const int* in_sizes, int n_in,
                              void* d_out, int out_size, void* d_ws, size_t ws_size,
                              hipStream_t stream) {
  const float* X  = (const float*)d_in[0];
  const float* Wq = (const float*)d_in[1];
  const float* Wk = (const float*)d_in[2];
  const float* Wv = (const float*)d_in[3];
  const float* Wo = (const float*)d_in[4];
  float* out = (float*)d_out;
  u16* wsu = (u16*)d_ws;
  float* L = (float*)(wsu + OFF_L);

  k_prep_x  <<<4096, 256, 0, stream>>>(X, wsu);
  k_prep_w  <<<1024, 256, 0, stream>>>(Wq, Wk, Wv, Wo, wsu);
  k_projg   <<<1536, 256, 0, stream>>>(wsu);
  k_pass1   <<<2048, 256, 0, stream>>>(wsu, L);
  k_scale_v <<<2048, 256, 0, stream>>>(wsu, L);
  k_pass2   <<<512,  256, 0, stream>>>(wsu);
  k_outproj <<<256,  256, 0, stream>>>(wsu, out);
}

// Round 11
// 201.544 us; speedup vs baseline: 1.4820x; 1.0453x over previous
//
#include <hip/hip_runtime.h>
#include <math.h>

namespace {

typedef unsigned short u16;
typedef unsigned int   u32;
typedef __bf16 bf16x8 __attribute__((ext_vector_type(8)));
typedef float  f32x4  __attribute__((ext_vector_type(4)));
typedef float  f32x16 __attribute__((ext_vector_type(16)));
typedef u32    u32x4  __attribute__((ext_vector_type(4)));

// ---- workspace layout (u16 element offsets) --------------------------------
constexpr size_t OFF_XH  = 0;          // [4096][1024] bf16 hi of X (dead after proj)
constexpr size_t OFF_WH  = 4194304;    // [3072 j=qkv*1024+h*64+k'][1024 d] hi
constexpr size_t OFF_WL  = 7340032;    //                                   lo
constexpr size_t OFF_QH  = 10485760;   // [32 bh][2048][64]
constexpr size_t OFF_QL  = 14680064;   // [32 bh][2048][64]
constexpr size_t OFF_KH  = 18874368;   // [32 bh][2048][64]
constexpr size_t OFF_VT  = 23068672;   // [32 bh][64][2048]
constexpr size_t OFF_WOT = 27262976;   // [1024 d'][1024 c]
constexpr size_t OFF_L   = 28311552;   // f32[65536] raw column sums (131072 u16)
constexpr size_t OFF_AVH = 0;          // aliases XH (dead after proj)
// end = 28,442,624 u16 = 56.9 MB  (< 65.3 MB proven safe)

constexpr size_t VT_ELEMS = (size_t)32 * 64 * 2048;       // 4,194,304

__device__ __forceinline__ u16 f2bf(float x) {            // RNE fp32 -> bf16
  union { float f; unsigned u; } v; v.f = x;
  unsigned r = v.u + 0x7FFFu + ((v.u >> 16) & 1u);
  return (u16)(r >> 16);
}
__device__ __forceinline__ float bf2f(u16 b) {
  union { unsigned u; float f; } v; v.u = (unsigned)b << 16; return v.f;
}
__device__ __forceinline__ bf16x8 frag(const u16* p) {
  return *reinterpret_cast<const bf16x8*>(p);
}
__device__ __forceinline__ f32x4 mfma16(bf16x8 a, bf16x8 b, f32x4 c) {
  return __builtin_amdgcn_mfma_f32_16x16x32_bf16(a, b, c, 0, 0, 0);
}
__device__ __forceinline__ f32x16 mfma32(bf16x8 a, bf16x8 b, f32x16 c) {
  return __builtin_amdgcn_mfma_f32_32x32x16_bf16(a, b, c, 0, 0, 0);
}
__device__ __forceinline__ void gload16(const void* g, void* l) {
  __builtin_amdgcn_global_load_lds(
      (const __attribute__((address_space(1))) u32*)g,
      (__attribute__((address_space(3))) u32*)l, 16, 0, 0);
}
__device__ __forceinline__ u32 cvtpk(float lo, float hi) {
  u32 r;
  asm("v_cvt_pk_bf16_f32 %0, %1, %2" : "=v"(r) : "v"(lo), "v"(hi));
  return r;
}
__device__ __forceinline__ void pswap(u32& a, u32& b) {
  asm("v_permlane32_swap_b32 %0, %1" : "+v"(a), "+v"(b));
}

// ---------------------------------------------------------------------------
// Prep X: X f32 -> Xh bf16 (hi only); blocks <64 also zero the L accumulator.
// ---------------------------------------------------------------------------
__global__ __launch_bounds__(256) void k_prep_x(
    const float* __restrict__ X, u16* __restrict__ wsu)
{
  u16* Xh = wsu + OFF_XH;
  const size_t i = ((size_t)blockIdx.x * 256 + threadIdx.x) * 4;  // 4096 blocks
  const float4 v = *(const float4*)&X[i];
  ushort4 hh;
  hh.x = f2bf(v.x); hh.y = f2bf(v.y); hh.z = f2bf(v.z); hh.w = f2bf(v.w);
  *(ushort4*)&Xh[i] = hh;
  if (blockIdx.x < 64) {                       // zero L: 64*256*4 = 65536 f32
    float* L = (float*)(wsu + OFF_L);
    const size_t li = ((size_t)blockIdx.x * 256 + threadIdx.x) * 4;
    *(float4*)&L[li] = make_float4(0.f, 0.f, 0.f, 0.f);
  }
}

// ---------------------------------------------------------------------------
// Prep weights: bx<768 -> transpose+hi/lo split W_{q,k,v} into WALL[j][d];
// bx>=768 -> transpose W_O into WOT[d'][c].
// ---------------------------------------------------------------------------
__global__ __launch_bounds__(256) void k_prep_w(
    const float* __restrict__ Wq, const float* __restrict__ Wk,
    const float* __restrict__ Wv, const float* __restrict__ Wo,
    u16* __restrict__ wsu)
{
  const int bx = blockIdx.x;                 // 1024
  const int tid = threadIdx.x;
  __shared__ float T[64][65];
  if (bx < 768) {                            // 768 = qkv(3)*h(16)*dchunk(16)
    const int qkv = bx >> 8, h = (bx >> 4) & 15, dc = bx & 15;
    const float* W = qkv == 0 ? Wq : qkv == 1 ? Wk : Wv;
    const int d0 = dc * 64;
    for (int l = 0; l < 16; ++l) {
      int idx = tid + l * 256; int r = idx >> 6, c = idx & 63;  // r=d, c=k'
      T[r][c] = W[((size_t)h * 1024 + d0 + r) * 64 + c];
    }
    __syncthreads();
    u16* Wh = wsu + OFF_WH;
    u16* Wl = wsu + OFF_WL;
    for (int l = 0; l < 16; ++l) {
      int idx = tid + l * 256; int r = idx >> 6, c = idx & 63;  // r=k', c=d
      float v = T[c][r];
      u16 hi = f2bf(v);
      size_t o = (size_t)((qkv * 16 + h) * 64 + r) * 1024 + d0 + c;
      Wh[o] = hi;
      Wl[o] = f2bf(v - bf2f(hi));
    }
  } else {                                   // 256 = cchunk(16)*dchunk(16)
    const int b2 = bx - 768;
    const int c0 = (b2 >> 4) * 64, dd0 = (b2 & 15) * 64;
    for (int l = 0; l < 16; ++l) {
      int idx = tid + l * 256; int r = idx >> 6, c = idx & 63;
      T[r][c] = Wo[(size_t)(c0 + r) * 1024 + dd0 + c];
    }
    __syncthreads();
    u16* WOT = wsu + OFF_WOT;
    for (int l = 0; l < 16; ++l) {
      int idx = tid + l * 256; int r = idx >> 6, c = idx & 63;
      WOT[(size_t)(dd0 + r) * 1024 + c0 + c] = f2bf(T[c][r]);
    }
  }
}

// ---------------------------------------------------------------------------
// Fused QKV projection: C[4096][3072] = Xh . (Wh+Wl), 2-term split expressed
// as a K'=2048 GEMM (k-tile t: d0=(t>>1)*64, plane=t&1).  128x128 tile,
// double-buffered stage-ahead (pass2's validated pattern), XOR-swizzled LDS
// (conflict-free ds_read_b128).  Grid 768 = 8 XCD x (3 ct x 32 mt).
// ---------------------------------------------------------------------------
__global__ __launch_bounds__(256, 2) void k_projg(u16* __restrict__ wsu)
{
  const int bid = blockIdx.x;                // 768
  const int xcd = bid & 7, local = bid >> 3; // local 0..95
  const int ct = xcd * 3 + local % 3;        // 24 col-tiles of 128
  const int mt = local / 3;                  // 32 row-tiles of 128
  const int gm0 = mt * 128;
  const int j0 = ct * 128;                   // row in WALL
  const int qkv = ct >> 3;

  const u16* XH = wsu + OFF_XH;
  const u16* WH = wsu + OFF_WH;
  const u16* WL = wsu + OFF_WL;

  __shared__ __align__(16) u16 lds[2][16384];  // [buf][A 128x64 | B 128x64]

  const int tid = threadIdx.x;
  const int w = tid >> 6, l = tid & 63, lr = l & 15, lg = l >> 4;
  const int wm = w >> 1, wn = w & 1;

  auto stage = [&](int buf, int t) {
    const int d0 = (t >> 1) * 64;
    const u16* Wp = (t & 1) ? WL : WH;
    #pragma unroll
    for (int it = 0; it < 8; ++it) {
      const int c = tid + it * 256;          // 0..2047 16B chunks
      const u16* src;
      if (c < 1024) {                        // A: X rows gm0..+127
        const int r = c >> 3, cl = c & 7;
        src = XH + (size_t)(gm0 + r) * 1024 + d0 + (cl ^ (r & 7)) * 8;
      } else {                               // B: W rows j0..+127 (this plane)
        const int cc = c - 1024;
        const int r = cc >> 3, cl = cc & 7;
        src = Wp + (size_t)(j0 + r) * 1024 + d0 + (cl ^ (r & 7)) * 8;
      }
      gload16(src, &lds[buf][0] + (size_t)c * 8);
    }
  };

  const f32x4 fz = {0.f, 0.f, 0.f, 0.f};
  f32x4 acc[4][4];
  for (int i = 0; i < 4; ++i) for (int j = 0; j < 4; ++j) acc[i][j] = fz;

  stage(0, 0);
  __syncthreads();
  int cur = 0;
  for (int t = 0; t < 32; ++t) {
    if (t < 31) stage(cur ^ 1, t + 1);       // overlap next-tile loads
    const u16* As = &lds[cur][0];
    const u16* Bs = &lds[cur][8192];
    #pragma unroll
    for (int ks = 0; ks < 2; ++ks) {
      bf16x8 a[4], b[4];
      #pragma unroll
      for (int mf = 0; mf < 4; ++mf) {
        const int row = wm * 64 + mf * 16 + lr;
        a[mf] = frag(As + row * 64 + ((ks * 4 + lg) ^ (row & 7)) * 8);
      }
      #pragma unroll
      for (int nf = 0; nf < 4; ++nf) {
        const int row = wn * 64 + nf * 16 + lr;
        b[nf] = frag(Bs + row * 64 + ((ks * 4 + lg) ^ (row & 7)) * 8);
      }
      #pragma unroll
      for (int nf = 0; nf < 4; ++nf)
        #pragma unroll
        for (int mf = 0; mf < 4; ++mf)
          acc[mf][nf] = mfma16(a[mf], b[nf], acc[mf][nf]);
    }
    __syncthreads();                         // drains gload_lds for buf^1
    cur ^= 1;
  }

  const int colbase = j0 + wn * 64;          // this wave's 64 cols = ONE head
  const int h = (colbase >> 6) & 15;
  if (qkv == 0) {        // Q: hi/lo planes [bh][n][64]
    u16* Ph = wsu + OFF_QH;
    u16* Pl = wsu + OFF_QL;
    #pragma unroll
    for (int mf = 0; mf < 4; ++mf)
      #pragma unroll
      for (int nf = 0; nf < 4; ++nf)
        #pragma unroll
        for (int r = 0; r < 4; ++r) {
          const float v = acc[mf][nf][r];
          const int gn = gm0 + wm * 64 + mf * 16 + lg * 4 + r;
          const int b = gn >> 11, n = gn & 2047;
          const int kp = nf * 16 + lr;
          const size_t o = ((size_t)(b * 16 + h) * 2048 + n) * 64 + kp;
          const u16 hi = f2bf(v);
          Ph[o] = hi;
          Pl[o] = f2bf(v - bf2f(hi));
        }
  } else if (qkv == 1) { // K: hi only
    u16* Ph = wsu + OFF_KH;
    #pragma unroll
    for (int mf = 0; mf < 4; ++mf)
      #pragma unroll
      for (int nf = 0; nf < 4; ++nf)
        #pragma unroll
        for (int r = 0; r < 4; ++r) {
          const int gn = gm0 + wm * 64 + mf * 16 + lg * 4 + r;
          const int b = gn >> 11, n = gn & 2047;
          const int kp = nf * 16 + lr;
          Ph[((size_t)(b * 16 + h) * 2048 + n) * 64 + kp] = f2bf(acc[mf][nf][r]);
        }
  } else {               // V: transposed store VT[bh][k'][n]
    u16* VT = wsu + OFF_VT;
    #pragma unroll
    for (int mf = 0; mf < 4; ++mf)
      #pragma unroll
      for (int nf = 0; nf < 4; ++nf) {
        const int gn = gm0 + wm * 64 + mf * 16 + lg * 4;
        const int b = gn >> 11, n = gn & 2047;
        const int kp = nf * 16 + lr;
        ushort4 p;
        p.x = f2bf(acc[mf][nf][0]); p.y = f2bf(acc[mf][nf][1]);
        p.z = f2bf(acc[mf][nf][2]); p.w = f2bf(acc[mf][nf][3]);
        *(ushort4*)&VT[((size_t)(b * 16 + h) * 64 + kp) * 2048 + n] = p;
      }
  }
}

// ---------------------------------------------------------------------------
// Pass 1 (i-split x4, 2-TERM: l_j = sum_i exp(Kh_j . (Qh+Ql)_i)), atomicAdd.
// [round-10 verbatim]
// ---------------------------------------------------------------------------
__global__ __launch_bounds__(256, 2) void k_pass1(
    u16* __restrict__ wsu, float* __restrict__ L)
{
  const int bid = blockIdx.x;                    // 2048
  const int swz = (bid & 7) * 256 + (bid >> 3);
  const int bh = swz >> 6;
  const int jtile = (swz >> 2) & 15;
  const int isl = swz & 3;
  const int j0 = jtile * 128;
  const u16* Qh = wsu + OFF_QH + (size_t)bh * 131072;
  const u16* Ql = wsu + OFF_QL + (size_t)bh * 131072;
  const u16* Kh = wsu + OFF_KH + (size_t)bh * 131072;

  __shared__ __align__(16) u16 lds[2][2][4096];   // [buf][Qhi,Qlo][64][64]

  const int tid = threadIdx.x;
  const int w = tid >> 6, l = tid & 63;
  const int il = l & 31, hi = l >> 5;

  bf16x8 kah[4];                                 // stationary K A-frags
  {
    const int jrow = j0 + w * 32 + il;
    #pragma unroll
    for (int ks = 0; ks < 4; ++ks)
      kah[ks] = frag(&Kh[(size_t)jrow * 64 + ks * 16 + hi * 8]);
  }

  auto stage = [&](int buf, int ic) {
    const int i0 = ic * 64;
    #pragma unroll
    for (int it = 0; it < 4; ++it) {
      const int c = tid + it * 256;              // 0..1023
      const int plane = c >> 9, cc = c & 511;
      const int r = cc >> 3, cl = cc & 7;
      const int sw8 = (cl ^ (r & 7)) * 8;        // inverse-swizzled source
      const u16* src = (plane ? Ql : Qh) + (size_t)(i0 + r) * 64 + sw8;
      gload16(src, &lds[buf][0][0] + (size_t)c * 8);
    }
  };

  const f32x16 fz16 = {0,0,0,0,0,0,0,0,0,0,0,0,0,0,0,0};
  float lsum[16] = {};
  const int icbase = isl * 8;

  stage(0, icbase);
  __syncthreads();
  int cur = 0;
  for (int ii = 0; ii < 8; ++ii) {
    if (ii < 7) stage(cur ^ 1, icbase + ii + 1);
    const u16* Qsh = &lds[cur][0][0];
    const u16* Qsl = &lds[cur][1][0];
    #pragma unroll
    for (int it2 = 0; it2 < 2; ++it2) {
      f32x16 s = fz16;
      const int qrow = it2 * 32 + il;
      #pragma unroll
      for (int ks = 0; ks < 4; ++ks) {
        const int ch = ((ks * 2 + hi) ^ (qrow & 7)) * 8;   // swizzled read
        s = mfma32(kah[ks], frag(&Qsh[qrow * 64 + ch]), s);
        s = mfma32(kah[ks], frag(&Qsl[qrow * 64 + ch]), s);
      }
      #pragma unroll
      for (int r = 0; r < 16; ++r) lsum[r] += __expf(s[r]);
    }
    __syncthreads();
    cur ^= 1;
  }

  #pragma unroll
  for (int r = 0; r < 16; ++r) {
    float v = lsum[r];
    v += __shfl_xor(v, 1);  v += __shfl_xor(v, 2);
    v += __shfl_xor(v, 4);  v += __shfl_xor(v, 8);
    v += __shfl_xor(v, 16);
    if (il == 0) {
      const int j = j0 + w * 32 + (r & 3) + 8 * (r >> 2) + 4 * hi;
      atomicAdd(&L[(size_t)bh * 2048 + j], v);
    }
  }
}

// ---------------------------------------------------------------------------
// Scale V^T by 1/l along n:  VT[bh][c][n] *= rcp(L[bh][n])  [round-10 verbatim]
// ---------------------------------------------------------------------------
__global__ __launch_bounds__(256) void k_scale_v(
    u16* __restrict__ wsu, const float* __restrict__ L)
{
  u16* VT = wsu + OFF_VT;
  const size_t vid = (size_t)blockIdx.x * 256 + threadIdx.x;  // 0..524287
  if (vid * 8 >= VT_ELEMS) return;
  const size_t base = vid * 8;
  const int n8 = (int)(vid & 255);
  const int bh = (int)(vid >> 14);
  ushort4 a = *(ushort4*)&VT[base];
  ushort4 b = *(ushort4*)&VT[base + 4];
  const float* Lp = L + (size_t)bh * 2048 + n8 * 8;
  a.x = f2bf(bf2f(a.x) * __builtin_amdgcn_rcpf(Lp[0]));
  a.y = f2bf(bf2f(a.y) * __builtin_amdgcn_rcpf(Lp[1]));
  a.z = f2bf(bf2f(a.z) * __builtin_amdgcn_rcpf(Lp[2]));
  a.w = f2bf(bf2f(a.w) * __builtin_amdgcn_rcpf(Lp[3]));
  b.x = f2bf(bf2f(b.x) * __builtin_amdgcn_rcpf(Lp[4]));
  b.y = f2bf(bf2f(b.y) * __builtin_amdgcn_rcpf(Lp[5]));
  b.z = f2bf(bf2f(b.z) * __builtin_amdgcn_rcpf(Lp[6]));
  b.w = f2bf(bf2f(b.w) * __builtin_amdgcn_rcpf(Lp[7]));
  *(ushort4*)&VT[base] = a;
  *(ushort4*)&VT[base + 4] = b;
}

// ---------------------------------------------------------------------------
// Pass 2 (4-wave, 2-TERM S, in-register P): AV[i][c] = sum_j exp(S_ij) V'[j][c]
// [round-10 verbatim]
// ---------------------------------------------------------------------------
__global__ __launch_bounds__(256, 2) void k_pass2(u16* __restrict__ wsu)
{
  const int bid = blockIdx.x;                  // 512
  const int swz = (bid & 7) * 64 + (bid >> 3);
  const int itile = swz & 15, bh = swz >> 4;
  const int i0 = itile * 128;
  const u16* Qh = wsu + OFF_QH + (size_t)bh * 131072;
  const u16* Ql = wsu + OFF_QL + (size_t)bh * 131072;
  const u16* Kh = wsu + OFF_KH + (size_t)bh * 131072;
  const u16* VT = wsu + OFF_VT + (size_t)bh * 131072;

  __shared__ __align__(16) u16 lds[2][2][4096];  // [buf][Kh,V][64][64]

  const int tid = threadIdx.x;
  const int w = tid >> 6, l = tid & 63;
  const int il = l & 31, hi = l >> 5;

  bf16x8 qbh[4], qbl[4];                       // stationary Q B-frags
  {
    const int irow = i0 + w * 32 + il;
    #pragma unroll
    for (int ks = 0; ks < 4; ++ks) {
      const size_t o = (size_t)irow * 64 + ks * 16 + hi * 8;
      qbh[ks] = frag(&Qh[o]);
      qbl[ks] = frag(&Ql[o]);
    }
  }

  auto stage = [&](int buf, int jc) {
    const int j0 = jc * 64;
    #pragma unroll
    for (int it = 0; it < 4; ++it) {
      const int c = tid + it * 256;            // 0..1023
      const int plane = c >> 9, cc = c & 511;
      const int r = cc >> 3, cl = cc & 7;
      const int sw8 = (cl ^ (r & 7)) * 8;
      const u16* src = plane == 0 ? Kh + (size_t)(j0 + r) * 64 + sw8
                                  : VT + (size_t)r * 2048 + j0 + sw8;
      gload16(src, &lds[buf][0][0] + (size_t)c * 8);
    }
  };

  const f32x16 fz16 = {0,0,0,0,0,0,0,0,0,0,0,0,0,0,0,0};
  f32x16 acc[2]; acc[0] = fz16; acc[1] = fz16;

  stage(0, 0);
  __syncthreads();
  int cur = 0;
  for (int jc = 0; jc < 32; ++jc) {
    if (jc < 31) stage(cur ^ 1, jc + 1);
    const u16* Ksh = &lds[cur][0][0];
    const u16* Vs  = &lds[cur][1][0];
    #pragma unroll
    for (int jt = 0; jt < 2; ++jt) {
      f32x16 s = fz16;
      const int jrow = jt * 32 + il;
      #pragma unroll
      for (int ks = 0; ks < 4; ++ks) {
        const int ch = ((ks * 2 + hi) ^ (jrow & 7)) * 8;
        bf16x8 ka = frag(&Ksh[jrow * 64 + ch]);
        s = mfma32(ka, qbh[ks], s);
        s = mfma32(ka, qbl[ks], s);
      }
      float p[16];
      #pragma unroll
      for (int r = 0; r < 16; ++r) p[r] = __expf(s[r]);
      u32 a0 = cvtpk(p[0],  p[1]),  b0 = cvtpk(p[4],  p[5]);
      u32 a1 = cvtpk(p[2],  p[3]),  b1 = cvtpk(p[6],  p[7]);
      u32 a2 = cvtpk(p[8],  p[9]),  b2 = cvtpk(p[12], p[13]);
      u32 a3 = cvtpk(p[10], p[11]), b3 = cvtpk(p[14], p[15]);
      pswap(a0, b0); pswap(a1, b1); pswap(a2, b2); pswap(a3, b3);
      u32x4 pw0 = {a0, a1, b0, b1};            // k = j 0..15 of this jt
      u32x4 pw1 = {a2, a3, b2, b3};            // k = j 16..31
      bf16x8 pa0 = __builtin_bit_cast(bf16x8, pw0);
      bf16x8 pa1 = __builtin_bit_cast(bf16x8, pw1);
      #pragma unroll
      for (int cb = 0; cb < 2; ++cb) {
        const int crow = cb * 32 + il;
        const int c0 = ((jt * 4 + 0 + hi) ^ (crow & 7)) * 8;
        const int c1 = ((jt * 4 + 2 + hi) ^ (crow & 7)) * 8;
        bf16x8 vb0 = frag(&Vs[crow * 64 + c0]);
        bf16x8 vb1 = frag(&Vs[crow * 64 + c1]);
        acc[cb] = mfma32(pa0, vb0, acc[cb]);
        acc[cb] = mfma32(pa1, vb1, acc[cb]);
      }
    }
    __syncthreads();
    cur ^= 1;
  }

  u16* AVh = wsu + OFF_AVH;                    // hi only (1-term outproj)
  #pragma unroll
  for (int cb = 0; cb < 2; ++cb)
    #pragma unroll
    for (int r = 0; r < 16; ++r) {
      const int iloc = (r & 3) + 8 * (r >> 2) + 4 * hi;
      const int g = i0 + w * 32 + iloc;
      const int c = cb * 32 + il;
      AVh[((size_t)bh * 2048 + g) * 64 + c] = f2bf(acc[cb][r]);
    }
}

// ---------------------------------------------------------------------------
// Output projection: Out = AVh[4096][1024] . WO  (1-term)
// Double-buffered stage-ahead + XOR-swizzled LDS (same mechanic as projg).
// ---------------------------------------------------------------------------
__global__ __launch_bounds__(256, 2) void k_outproj(
    const u16* __restrict__ wsu, float* __restrict__ Out)
{
  const int bx = blockIdx.x;                 // 256 = gm(32) * dn(8)
  const int gm = bx >> 3, dn = bx & 7;       // dn == bid&7: per-XCD WOT strip
  const int g0 = gm * 128, d0 = dn * 128;
  const u16* AVh = wsu + OFF_AVH;
  const u16* WOT = wsu + OFF_WOT;

  __shared__ __align__(16) u16 lds[2][16384];  // [buf][A 128x64 | B 128x64]

  const int tid = threadIdx.x;
  const int w = tid >> 6, l = tid & 63, lr = l & 15, lg = l >> 4;
  const int wm = w >> 1, wn = w & 1;

  auto stage = [&](int buf, int t) {
    const int c0 = t * 64;
    #pragma unroll
    for (int it = 0; it < 8; ++it) {
      const int c = tid + it * 256;          // 0..2047 16B chunks
      const u16* src;
      if (c < 1024) {                        // A: AVh rows g0..+127
        const int r = c >> 3, cl = c & 7;
        src = AVh + (size_t)(g0 + r) * 1024 + c0 + (cl ^ (r & 7)) * 8;
      } else {                               // B: WOT rows d0..+127
        const int cc = c - 1024;
        const int r = cc >> 3, cl = cc & 7;
        src = WOT + (size_t)(d0 + r) * 1024 + c0 + (cl ^ (r & 7)) * 8;
      }
      gload16(src, &lds[buf][0] + (size_t)c * 8);
    }
  };

  const f32x4 fz = {0.f, 0.f, 0.f, 0.f};
  f32x4 acc[4][4];
  for (int i = 0; i < 4; ++i) for (int j = 0; j < 4; ++j) acc[i][j] = fz;

  stage(0, 0);
  __syncthreads();
  int cur = 0;
  for (int t = 0; t < 16; ++t) {
    if (t < 15) stage(cur ^ 1, t + 1);
    const u16* As = &lds[cur][0];
    const u16* Bs = &lds[cur][8192];
    #pragma unroll
    for (int ks = 0; ks < 2; ++ks) {
      bf16x8 a[4], b[4];
      #pragma unroll
      for (int mf = 0; mf < 4; ++mf) {
        const int row = wm * 64 + mf * 16 + lr;
        a[mf] = frag(As + row * 64 + ((ks * 4 + lg) ^ (row & 7)) * 8);
      }
      #pragma unroll
      for (int nf = 0; nf < 4; ++nf) {
        const int row = wn * 64 + nf * 16 + lr;
        b[nf] = frag(Bs + row * 64 + ((ks * 4 + lg) ^ (row & 7)) * 8);
      }
      #pragma unroll
      for (int nf = 0; nf < 4; ++nf)
        #pragma unroll
        for (int mf = 0; mf < 4; ++mf)
          acc[mf][nf] = mfma16(a[mf], b[nf], acc[mf][nf]);
    }
    __syncthreads();
    cur ^= 1;
  }
  #pragma unroll
  for (int mf = 0; mf < 4; ++mf)
    #pragma unroll
    for (int nf = 0; nf < 4; ++nf)
      #pragma unroll
      for (int r = 0; r < 4; ++r) {
        const int g = g0 + wm * 64 + mf * 16 + lg * 4 + r;
        const int d = d0 + wn * 64 + nf * 16 + lr;
        Out[(size_t)g * 1024 + d] = acc[mf][nf][r];
      }
}

} // anonymous namespace

extern "C" void kernel_launch(void* const* d_in, const int* in_sizes, int n_in,
                              void* d_out, int out_size, void* d_ws, size_t ws_size,
                              hipStream_t stream) {
  const float* X  = (const float*)d_in[0];
  const float* Wq = (const float*)d_in[1];
  const float* Wk = (const float*)d_in[2];
  const float* Wv = (const float*)d_in[3];
  const float* Wo = (const float*)d_in[4];
  float* out = (float*)d_out;
  u16* wsu = (u16*)d_ws;
  float* L = (float*)(wsu + OFF_L);

  k_prep_x  <<<4096, 256, 0, stream>>>(X, wsu);
  k_prep_w  <<<1024, 256, 0, stream>>>(Wq, Wk, Wv, Wo, wsu);
  k_projg   <<<768,  256, 0, stream>>>(wsu);
  k_pass1   <<<2048, 256, 0, stream>>>(wsu, L);
  k_scale_v <<<2048, 256, 0, stream>>>(wsu, L);
  k_pass2   <<<512,  256, 0, stream>>>(wsu);
  k_outproj <<<256,  256, 0, stream>>>(wsu, out);
}